// Round 12
// baseline (818.965 us; speedup 1.0000x reference)
//
#include <hip/hip_runtime.h>
#include <math.h>

#define NN 100000
#define NE 1000000
#define DH 64
constexpr int ETOT = NE + NN;
constexpr int CHUNK = 100;
constexpr int NCHUNK = (NN + CHUNK - 1) / CHUNK;   // 1000

typedef _Float16 half_t;

// AoS edge record: {int src; float e0; float e1; int pad} stored as int4

// ---------------- degree ----------------

__global__ void k_zero_init(int* __restrict__ deg) {
    int i = blockIdx.x * blockDim.x + threadIdx.x;
    if (i < NN) deg[i] = 0;
}

__global__ void k_deg(const int* __restrict__ ei, int* __restrict__ deg) {
    int e = blockIdx.x * blockDim.x + threadIdx.x;
    if (e < NE) atomicAdd(&deg[ei[NE + e]], 1);
}

// ---------------- chunked prefix scan (scalar) ----------------

__global__ void k_scan_a(const int* __restrict__ deg, int* __restrict__ part) {
    int c = blockIdx.x * blockDim.x + threadIdx.x;
    if (c >= NCHUNK) return;
    int lo = c * CHUNK;
    int hi = lo + CHUNK; if (hi > NN) hi = NN;
    int s = 0;
    for (int i = lo; i < hi; i++) s += deg[i];
    part[c] = s;
}

__global__ void k_scan_b(int* __restrict__ part) {
    if (threadIdx.x || blockIdx.x) return;
    int run = 0;
    for (int i = 0; i < NCHUNK; i++) { int t = part[i]; part[i] = run; run += t; }
}

__global__ void k_scan_c(const int* __restrict__ deg, const int* __restrict__ part,
                         int* __restrict__ row, int* __restrict__ cursor) {
    int c = blockIdx.x * blockDim.x + threadIdx.x;
    if (c >= NCHUNK) return;
    int lo = c * CHUNK;
    int hi = lo + CHUNK; if (hi > NN) hi = NN;
    int run = part[c];
    for (int i = lo; i < hi; i++) {
        int r = run + i;
        row[i] = r;
        cursor[i] = r;
        run += deg[i];
    }
    if (c == NCHUNK - 1) row[NN] = run + NN;
}

__global__ void k_fill_csr(const int* __restrict__ ei, const float* __restrict__ ea,
                           int* __restrict__ cursor, int4* __restrict__ csr) {
    int e = blockIdx.x * blockDim.x + threadIdx.x;
    if (e < NE) {
        int s = ei[e];
        int d = ei[NE + e];
        int pos = atomicAdd(&cursor[d], 1);
        int4 rec;
        rec.x = s;
        rec.y = __float_as_int(ea[2 * e]);
        rec.z = __float_as_int(ea[2 * e + 1]);
        rec.w = 0;
        csr[pos] = rec;
    }
}

__global__ void k_fill_self(const int* __restrict__ deg, const int* __restrict__ row,
                            int4* __restrict__ csr) {
    int n = blockIdx.x * blockDim.x + threadIdx.x;
    if (n >= NN) return;
    int r0 = row[n];
    int dg = deg[n];
    float s0 = 0.f, s1 = 0.f;
    for (int j = r0; j < r0 + dg; j++) {
        int4 rec = csr[j];
        s0 += __int_as_float(rec.y);
        s1 += __int_as_float(rec.z);
    }
    float dv = fmaxf((float)dg, 1.0f);
    int4 self;
    self.x = n;
    self.y = __float_as_int(s0 / dv);
    self.z = __float_as_int(s1 / dv);
    self.w = 0;
    csr[r0 + dg] = self;
}

// ---------------- encoder: h = relu(x @ enc_W + enc_b), writes f32 + fp16 ----------------

__global__ void k_encoder(const float* __restrict__ x, const float* __restrict__ W,
                          const float* __restrict__ b, float* __restrict__ h,
                          half_t* __restrict__ h16) {
    int idx = blockIdx.x * blockDim.x + threadIdx.x;
    int n = idx >> 6, d = idx & 63;
    if (n < NN) {
        float v = x[2 * n] * W[d] + x[2 * n + 1] * W[DH + d] + b[d];
        v = fmaxf(v, 0.f);
        h[idx] = v;
        h16[idx] = (half_t)v;
    }
}

// ---------------- fused prep (all 3 layers) ----------------

__global__ void k_prep(const float* __restrict__ lw0, const float* __restrict__ as0,
                       const float* __restrict__ ad0, const float* __restrict__ ew0,
                       const float* __restrict__ ae0,
                       const float* __restrict__ lw1, const float* __restrict__ as1,
                       const float* __restrict__ ad1, const float* __restrict__ ew1,
                       const float* __restrict__ ae1,
                       const float* __restrict__ lw2, const float* __restrict__ as2,
                       const float* __restrict__ ad2, const float* __restrict__ ew2,
                       const float* __restrict__ ae2,
                       float* __restrict__ wsrc, float* __restrict__ wdst,
                       float* __restrict__ coef) {
    int L = blockIdx.x;
    int k = threadIdx.x;
    if (k >= DH) return;
    const float* lw = (L == 0) ? lw0 : (L == 1) ? lw1 : lw2;
    const float* as = (L == 0) ? as0 : (L == 1) ? as1 : as2;
    const float* ad = (L == 0) ? ad0 : (L == 1) ? ad1 : ad2;
    const float* ew = (L == 0) ? ew0 : (L == 1) ? ew1 : ew2;
    const float* ae = (L == 0) ? ae0 : (L == 1) ? ae1 : ae2;
    int H = (L < 2) ? 4 : 1;
    int C = H * DH;
    int wo = (L == 0) ? 0 : (L == 1) ? 256 : 512;
    for (int h = 0; h < H; h++) {
        float ss = 0.f, sd = 0.f;
        for (int d = 0; d < DH; d++) {
            float w = lw[(size_t)k * C + h * DH + d];
            ss += w * as[h * DH + d];
            sd += w * ad[h * DH + d];
        }
        wsrc[wo + k * H + h] = ss;
        wdst[wo + k * H + h] = sd;
    }
    if (k == 0) {
        int co = (L == 0) ? 0 : (L == 1) ? 8 : 16;
        for (int w = 0; w < 2; w++)
            for (int h = 0; h < H; h++) {
                float s = 0.f;
                for (int d = 0; d < DH; d++)
                    s += ew[w * H * DH + h * DH + d] * ae[h * DH + d];
                coef[co + w * H + h] = s;
            }
    }
}

// ---------------- a_src/a_dst directly from h: one thread per node ----------------

template <int H>
__global__ void k_att_h(const float* __restrict__ h, const float* __restrict__ wsrc,
                        const float* __restrict__ wdst,
                        float* __restrict__ a_src, float* __restrict__ a_dst) {
    int n = blockIdx.x * blockDim.x + threadIdx.x;
    if (n >= NN) return;
    float as[H], ad[H];
#pragma unroll
    for (int hh = 0; hh < H; hh++) { as[hh] = 0.f; ad[hh] = 0.f; }
    const float* hr = h + (size_t)n * DH;
    for (int k = 0; k < DH; k++) {
        float hv = hr[k];
#pragma unroll
        for (int hh = 0; hh < H; hh++) {
            as[hh] += hv * wsrc[k * H + hh];
            ad[hh] += hv * wdst[k * H + hh];
        }
    }
#pragma unroll
    for (int hh = 0; hh < H; hh++) {
        a_src[n * H + hh] = as[hh];
        a_dst[n * H + hh] = ad[hh];
    }
}

// ---------------- per-node den + normalized alpha (fp16): one THREAD per node ----------------

template <int H>
__global__ void k_mden(const int* __restrict__ row, const int4* __restrict__ csr,
                       const float* __restrict__ a_src, const float* __restrict__ a_dst,
                       const float* __restrict__ coef, half_t* __restrict__ abuf) {
    int n = blockIdx.x * blockDim.x + threadIdx.x;
    if (n >= NN) return;
    int r0 = row[n], r1 = row[n + 1];
    float ad[H], cf[2 * H], den[H];
#pragma unroll
    for (int h = 0; h < H; h++) { ad[h] = a_dst[n * H + h]; den[h] = 0.f; }
#pragma unroll
    for (int i = 0; i < 2 * H; i++) cf[i] = coef[i];
    for (int j = r0; j < r1; j++) {
        int4 rec = csr[j];
        int s = rec.x;
        float e0 = __int_as_float(rec.y), e1 = __int_as_float(rec.z);
#pragma unroll
        for (int h = 0; h < H; h++) {
            float lg = a_src[s * H + h] + ad[h] + e0 * cf[h] + e1 * cf[H + h];
            lg = (lg > 0.f) ? lg : 0.2f * lg;
            den[h] += __expf(lg);
        }
    }
    float inv[H];
#pragma unroll
    for (int h = 0; h < H; h++) inv[h] = 1.f / (den[h] + 1e-16f);
    for (int j = r0; j < r1; j++) {
        int4 rec = csr[j];
        int s = rec.x;
        float e0 = __int_as_float(rec.y), e1 = __int_as_float(rec.z);
        half_t a4[H];
#pragma unroll
        for (int h = 0; h < H; h++) {
            float lg = a_src[s * H + h] + ad[h] + e0 * cf[h] + e1 * cf[H + h];
            lg = (lg > 0.f) ? lg : 0.2f * lg;
            a4[h] = (half_t)(__expf(lg) * inv[h]);
        }
        if constexpr (H == 4) {
            *(float2*)(abuf + (size_t)j * 4) = *(float2*)a4;
        } else {
            abuf[j] = a4[0];
        }
    }
}

// ---------------- aggregate on h: one WAVE per node, lane = k, 4-edge pipelined ----------------

template <int H>
__global__ void k_agg_h(const int* __restrict__ row, const int4* __restrict__ csr,
                        const half_t* __restrict__ abuf, const half_t* __restrict__ h16,
                        half_t* __restrict__ agg) {
    int gid = blockIdx.x * blockDim.x + threadIdx.x;
    int n = gid >> 6;
    int lane = gid & 63;
    if (n >= NN) return;
    int r0 = row[n], r1 = row[n + 1];
    float acc[H];
#pragma unroll
    for (int h = 0; h < H; h++) acc[h] = 0.f;
    int j = r0;
    for (; j + 4 <= r1; j += 4) {
        int s0 = csr[j].x, s1 = csr[j + 1].x, s2 = csr[j + 2].x, s3 = csr[j + 3].x;
        float av[4][H];
        if constexpr (H == 4) {
            float2 r0v = *(const float2*)(abuf + (size_t)(j + 0) * 4);
            float2 r1v = *(const float2*)(abuf + (size_t)(j + 1) * 4);
            float2 r2v = *(const float2*)(abuf + (size_t)(j + 2) * 4);
            float2 r3v = *(const float2*)(abuf + (size_t)(j + 3) * 4);
            const half_t* p0 = (const half_t*)&r0v;
            const half_t* p1 = (const half_t*)&r1v;
            const half_t* p2 = (const half_t*)&r2v;
            const half_t* p3 = (const half_t*)&r3v;
#pragma unroll
            for (int h = 0; h < 4; h++) {
                av[0][h] = (float)p0[h]; av[1][h] = (float)p1[h];
                av[2][h] = (float)p2[h]; av[3][h] = (float)p3[h];
            }
        } else {
            av[0][0] = (float)abuf[j];     av[1][0] = (float)abuf[j + 1];
            av[2][0] = (float)abuf[j + 2]; av[3][0] = (float)abuf[j + 3];
        }
        float hv0 = (float)h16[(size_t)s0 * DH + lane];
        float hv1 = (float)h16[(size_t)s1 * DH + lane];
        float hv2 = (float)h16[(size_t)s2 * DH + lane];
        float hv3 = (float)h16[(size_t)s3 * DH + lane];
#pragma unroll
        for (int h = 0; h < H; h++) acc[h] += av[0][h] * hv0;
#pragma unroll
        for (int h = 0; h < H; h++) acc[h] += av[1][h] * hv1;
#pragma unroll
        for (int h = 0; h < H; h++) acc[h] += av[2][h] * hv2;
#pragma unroll
        for (int h = 0; h < H; h++) acc[h] += av[3][h] * hv3;
    }
    for (; j < r1; j++) {
        int s = csr[j].x;
        float av[H];
        if constexpr (H == 4) {
            float2 raw = *(const float2*)(abuf + (size_t)j * 4);
            const half_t* ap = (const half_t*)&raw;
#pragma unroll
            for (int h = 0; h < H; h++) av[h] = (float)ap[h];
        } else {
            av[0] = (float)abuf[j];
        }
        float hv = (float)h16[(size_t)s * DH + lane];
#pragma unroll
        for (int h = 0; h < H; h++) acc[h] += av[h] * hv;
    }
#pragma unroll
    for (int h = 0; h < H; h++)
        agg[(size_t)n * (H * DH) + h * DH + lane] = (half_t)acc[h];
}

// ---------------- out = mean_h(agg_h @ W_h) + bias, relu, +res; 4 nodes x 4 cols ----------------
// Narrowed from 8 to 4 cols/thread: 2x grid (occupancy 22%->~50%), total L1 W-traffic
// invariant (node-group unchanged), accumulation order per output identical.

template <int H>
__global__ void k_out(const half_t* __restrict__ agg, const float* __restrict__ lin_W,
                      const float* __restrict__ bias, const float* __restrict__ hin,
                      float* __restrict__ hout, half_t* __restrict__ h16out) {
    constexpr int C = H * DH;
    constexpr int TPN = DH / 4;                // 16 threads per 4-node group
    int gid = blockIdx.x * blockDim.x + threadIdx.x;
    int nb = gid / TPN;
    int c0 = (gid % TPN) * 4;
    if (nb >= NN / 4) return;
    int n0 = nb * 4;
    float acc[4][4];
#pragma unroll
    for (int i = 0; i < 4; i++)
#pragma unroll
        for (int j = 0; j < 4; j++) acc[i][j] = 0.f;
#pragma unroll
    for (int h = 0; h < H; h++) {
        for (int q = 0; q < DH / 4; q++) {
            float areg[4][4];
#pragma unroll
            for (int i = 0; i < 4; i++) {
                float2 raw = *(const float2*)(agg + (size_t)(n0 + i) * C + h * DH + q * 4);
                const half_t* ap = (const half_t*)&raw;
                areg[i][0] = (float)ap[0]; areg[i][1] = (float)ap[1];
                areg[i][2] = (float)ap[2]; areg[i][3] = (float)ap[3];
            }
#pragma unroll
            for (int t = 0; t < 4; t++) {
                int k = q * 4 + t;
                float4 w = *(const float4*)(lin_W + (size_t)k * C + h * DH + c0);
                float wv[4] = {w.x, w.y, w.z, w.w};
#pragma unroll
                for (int i = 0; i < 4; i++) {
                    float av = areg[i][t];
#pragma unroll
                    for (int j = 0; j < 4; j++) acc[i][j] += av * wv[j];
                }
            }
        }
    }
    float bv[4];
#pragma unroll
    for (int j = 0; j < 4; j++) bv[j] = bias[c0 + j];
#pragma unroll
    for (int i = 0; i < 4; i++) {
        const float* rp = hin + (size_t)(n0 + i) * DH + c0;
        float ov[4];
        half_t hv[4];
#pragma unroll
        for (int j = 0; j < 4; j++) {
            float v = acc[i][j] * (1.0f / H) + bv[j];
            v = fmaxf(v, 0.f) + rp[j];
            ov[j] = v;
            hv[j] = (half_t)v;
        }
        *(float4*)(hout + (size_t)(n0 + i) * DH + c0) = make_float4(ov[0], ov[1], ov[2], ov[3]);
        *(float2*)(h16out + (size_t)(n0 + i) * DH + c0) = *(float2*)hv;
    }
}

// ---------------- final MLP head ----------------

__global__ void k_head_s(const float* __restrict__ h, const float* __restrict__ fc1_W,
                         const float* __restrict__ fc1_b, const float* __restrict__ fc2_W,
                         const float* __restrict__ fc2_b, float* __restrict__ out) {
    int n = blockIdx.x * blockDim.x + threadIdx.x;
    if (n >= NN) return;
    float y[32];
#pragma unroll
    for (int c = 0; c < 32; c++) y[c] = fc1_b[c];
    for (int k = 0; k < DH; k++) {
        float hk = h[n * DH + k];
#pragma unroll
        for (int c = 0; c < 32; c++) y[c] += hk * fc1_W[k * 32 + c];
    }
    float o0 = fc2_b[0], o1 = fc2_b[1];
#pragma unroll
    for (int c = 0; c < 32; c++) {
        float yr = fmaxf(y[c], 0.f);
        o0 += yr * fc2_W[c * 2];
        o1 += yr * fc2_W[c * 2 + 1];
    }
    out[2 * n] = tanhf(o0);
    out[2 * n + 1] = tanhf(o1);
}

// ---------------- launch ----------------

extern "C" void kernel_launch(void* const* d_in, const int* in_sizes, int n_in,
                              void* d_out, int out_size, void* d_ws, size_t ws_size,
                              hipStream_t stream) {
    const float* x     = (const float*)d_in[0];
    const int*   ei    = (const int*)d_in[1];
    const float* ea    = (const float*)d_in[2];
    const float* enc_W = (const float*)d_in[3];
    const float* enc_b = (const float*)d_in[4];
    const float* lin_W[3]    = {(const float*)d_in[5],  (const float*)d_in[11], (const float*)d_in[17]};
    const float* att_src[3]  = {(const float*)d_in[6],  (const float*)d_in[12], (const float*)d_in[18]};
    const float* att_dst[3]  = {(const float*)d_in[7],  (const float*)d_in[13], (const float*)d_in[19]};
    const float* edge_W[3]   = {(const float*)d_in[8],  (const float*)d_in[14], (const float*)d_in[20]};
    const float* att_edge[3] = {(const float*)d_in[9],  (const float*)d_in[15], (const float*)d_in[21]};
    const float* bias[3]     = {(const float*)d_in[10], (const float*)d_in[16], (const float*)d_in[22]};
    const float* fc1_W = (const float*)d_in[23];
    const float* fc1_b = (const float*)d_in[24];
    const float* fc2_W = (const float*)d_in[25];
    const float* fc2_b = (const float*)d_in[26];
    float* out = (float*)d_out;

    char* p = (char*)d_ws;
    auto alloc = [&](size_t bytes) -> void* {
        void* r = (void*)p;
        p += (bytes + 255) & ~(size_t)255;
        return r;
    };
    int*    deg    = (int*)alloc((size_t)NN * 4);
    int*    part   = (int*)alloc((size_t)NCHUNK * 4);
    int*    row    = (int*)alloc((size_t)(NN + 1) * 4);
    int*    cursor = (int*)alloc((size_t)NN * 4);
    int4*   csr    = (int4*)alloc((size_t)ETOT * 16);
    float*  a_srcB = (float*)alloc((size_t)NN * 4 * 4);
    float*  a_dstB = (float*)alloc((size_t)NN * 4 * 4);
    float*  wsrcA  = (float*)alloc(576 * 4);
    float*  wdstA  = (float*)alloc(576 * 4);
    float*  coefA  = (float*)alloc(18 * 4);
    half_t* abuf   = (half_t*)alloc((size_t)ETOT * 4 * 2);
    half_t* aggB   = (half_t*)alloc((size_t)NN * 256 * 2);
    half_t* h16    = (half_t*)alloc((size_t)NN * DH * 2);
    float*  hA     = (float*)alloc((size_t)NN * DH * 4);
    float*  hB     = (float*)alloc((size_t)NN * DH * 4);

    const int BT = 256;
    const int nodeBlocks  = (NN + BT - 1) / BT;
    const int edgeBlocks  = (NE + BT - 1) / BT;
    const int chunkBlocks = (NCHUNK + BT - 1) / BT;
    const int ndBlocks    = (NN * DH + BT - 1) / BT;
    const int nodeWaveBlocks = (NN * 64 + BT - 1) / BT;
    const int outBlocks   = ((NN / 4) * (DH / 4) + BT - 1) / BT;   // 4-col threads

    k_zero_init<<<nodeBlocks, BT, 0, stream>>>(deg);
    k_deg<<<edgeBlocks, BT, 0, stream>>>(ei, deg);
    k_scan_a<<<chunkBlocks, BT, 0, stream>>>(deg, part);
    k_scan_b<<<1, 64, 0, stream>>>(part);
    k_scan_c<<<chunkBlocks, BT, 0, stream>>>(deg, part, row, cursor);
    k_fill_csr<<<edgeBlocks, BT, 0, stream>>>(ei, ea, cursor, csr);
    k_fill_self<<<nodeBlocks, BT, 0, stream>>>(deg, row, csr);
    k_encoder<<<ndBlocks, BT, 0, stream>>>(x, enc_W, enc_b, hA, h16);
    k_prep<<<3, 64, 0, stream>>>(lin_W[0], att_src[0], att_dst[0], edge_W[0], att_edge[0],
                                 lin_W[1], att_src[1], att_dst[1], edge_W[1], att_edge[1],
                                 lin_W[2], att_src[2], att_dst[2], edge_W[2], att_edge[2],
                                 wsrcA, wdstA, coefA);

    float* hin = hA;
    float* hout = hB;

    for (int L = 0; L < 3; L++) {
        const float* ws = wsrcA + ((L == 0) ? 0 : (L == 1) ? 256 : 512);
        const float* wd = wdstA + ((L == 0) ? 0 : (L == 1) ? 256 : 512);
        const float* cf = coefA + ((L == 0) ? 0 : (L == 1) ? 8 : 16);
        if (L < 2) {
            constexpr int H = 4;
            k_att_h<H><<<nodeBlocks, BT, 0, stream>>>(hin, ws, wd, a_srcB, a_dstB);
            k_mden<H><<<nodeBlocks, BT, 0, stream>>>(row, csr, a_srcB, a_dstB, cf, abuf);
            k_agg_h<H><<<nodeWaveBlocks, BT, 0, stream>>>(row, csr, abuf, h16, aggB);
            k_out<H><<<outBlocks, BT, 0, stream>>>(aggB, lin_W[L], bias[L], hin, hout, h16);
        } else {
            constexpr int H = 1;
            k_att_h<H><<<nodeBlocks, BT, 0, stream>>>(hin, ws, wd, a_srcB, a_dstB);
            k_mden<H><<<nodeBlocks, BT, 0, stream>>>(row, csr, a_srcB, a_dstB, cf, abuf);
            k_agg_h<H><<<nodeWaveBlocks, BT, 0, stream>>>(row, csr, abuf, h16, aggB);
            k_out<H><<<outBlocks, BT, 0, stream>>>(aggB, lin_W[L], bias[L], hin, hout, h16);
        }
        float* t = hin; hin = hout; hout = t;
    }
    k_head_s<<<nodeBlocks, BT, 0, stream>>>(hin, fc1_W, fc1_b, fc2_W, fc2_b, out);
}

// Round 13
// 745.280 us; speedup vs baseline: 1.0989x; 1.0989x over previous
//
#include <hip/hip_runtime.h>
#include <math.h>

#define NN 100000
#define NE 1000000
#define DH 64
constexpr int ETOT = NE + NN;
constexpr int CHUNK = 100;
constexpr int NCHUNK = (NN + CHUNK - 1) / CHUNK;   // 1000

typedef _Float16 half_t;

// AoS edge record: {int src; float e0; float e1; int pad} stored as int4

// ---------------- degree ----------------

__global__ void k_zero_init(int* __restrict__ deg) {
    int i = blockIdx.x * blockDim.x + threadIdx.x;
    if (i < NN) deg[i] = 0;
}

__global__ void k_deg(const int* __restrict__ ei, int* __restrict__ deg) {
    int e = blockIdx.x * blockDim.x + threadIdx.x;
    if (e < NE) atomicAdd(&deg[ei[NE + e]], 1);
}

// ---------------- chunked prefix scan (scalar) ----------------

__global__ void k_scan_a(const int* __restrict__ deg, int* __restrict__ part) {
    int c = blockIdx.x * blockDim.x + threadIdx.x;
    if (c >= NCHUNK) return;
    int lo = c * CHUNK;
    int hi = lo + CHUNK; if (hi > NN) hi = NN;
    int s = 0;
    for (int i = lo; i < hi; i++) s += deg[i];
    part[c] = s;
}

__global__ void k_scan_b(int* __restrict__ part) {
    if (threadIdx.x || blockIdx.x) return;
    int run = 0;
    for (int i = 0; i < NCHUNK; i++) { int t = part[i]; part[i] = run; run += t; }
}

__global__ void k_scan_c(const int* __restrict__ deg, const int* __restrict__ part,
                         int* __restrict__ row, int* __restrict__ cursor) {
    int c = blockIdx.x * blockDim.x + threadIdx.x;
    if (c >= NCHUNK) return;
    int lo = c * CHUNK;
    int hi = lo + CHUNK; if (hi > NN) hi = NN;
    int run = part[c];
    for (int i = lo; i < hi; i++) {
        int r = run + i;
        row[i] = r;
        cursor[i] = r;
        run += deg[i];
    }
    if (c == NCHUNK - 1) row[NN] = run + NN;
}

__global__ void k_fill_csr(const int* __restrict__ ei, const float* __restrict__ ea,
                           int* __restrict__ cursor, int4* __restrict__ csr) {
    int e = blockIdx.x * blockDim.x + threadIdx.x;
    if (e < NE) {
        int s = ei[e];
        int d = ei[NE + e];
        int pos = atomicAdd(&cursor[d], 1);
        int4 rec;
        rec.x = s;
        rec.y = __float_as_int(ea[2 * e]);
        rec.z = __float_as_int(ea[2 * e + 1]);
        rec.w = 0;
        csr[pos] = rec;
    }
}

__global__ void k_fill_self(const int* __restrict__ deg, const int* __restrict__ row,
                            int4* __restrict__ csr) {
    int n = blockIdx.x * blockDim.x + threadIdx.x;
    if (n >= NN) return;
    int r0 = row[n];
    int dg = deg[n];
    float s0 = 0.f, s1 = 0.f;
    for (int j = r0; j < r0 + dg; j++) {
        int4 rec = csr[j];
        s0 += __int_as_float(rec.y);
        s1 += __int_as_float(rec.z);
    }
    float dv = fmaxf((float)dg, 1.0f);
    int4 self;
    self.x = n;
    self.y = __float_as_int(s0 / dv);
    self.z = __float_as_int(s1 / dv);
    self.w = 0;
    csr[r0 + dg] = self;
}

// ---------------- encoder: h = relu(x @ enc_W + enc_b), writes f32 + fp16 ----------------

__global__ void k_encoder(const float* __restrict__ x, const float* __restrict__ W,
                          const float* __restrict__ b, float* __restrict__ h,
                          half_t* __restrict__ h16) {
    int idx = blockIdx.x * blockDim.x + threadIdx.x;
    int n = idx >> 6, d = idx & 63;
    if (n < NN) {
        float v = x[2 * n] * W[d] + x[2 * n + 1] * W[DH + d] + b[d];
        v = fmaxf(v, 0.f);
        h[idx] = v;
        h16[idx] = (half_t)v;
    }
}

// ---------------- fused prep (all 3 layers) + fp16 lin_W conversion ----------------
// wsrc/wdst: L0 [0,256), L1 [256,512), L2 [512,576). coef: L0 [0,8), L1 [8,16), L2 [16,18).
// lin16: L0 at 0, L1 at 16384, L2 at 32768 (same [k][C] layout as lin_W).

__global__ void k_prep(const float* __restrict__ lw0, const float* __restrict__ as0,
                       const float* __restrict__ ad0, const float* __restrict__ ew0,
                       const float* __restrict__ ae0,
                       const float* __restrict__ lw1, const float* __restrict__ as1,
                       const float* __restrict__ ad1, const float* __restrict__ ew1,
                       const float* __restrict__ ae1,
                       const float* __restrict__ lw2, const float* __restrict__ as2,
                       const float* __restrict__ ad2, const float* __restrict__ ew2,
                       const float* __restrict__ ae2,
                       float* __restrict__ wsrc, float* __restrict__ wdst,
                       float* __restrict__ coef, half_t* __restrict__ lin16) {
    int L = blockIdx.x;
    int k = threadIdx.x;
    if (k >= DH) return;
    const float* lw = (L == 0) ? lw0 : (L == 1) ? lw1 : lw2;
    const float* as = (L == 0) ? as0 : (L == 1) ? as1 : as2;
    const float* ad = (L == 0) ? ad0 : (L == 1) ? ad1 : ad2;
    const float* ew = (L == 0) ? ew0 : (L == 1) ? ew1 : ew2;
    const float* ae = (L == 0) ? ae0 : (L == 1) ? ae1 : ae2;
    int H = (L < 2) ? 4 : 1;
    int C = H * DH;
    int wo = (L == 0) ? 0 : (L == 1) ? 256 : 512;
    int lo16 = (L == 0) ? 0 : (L == 1) ? 16384 : 32768;
    for (int h = 0; h < H; h++) {
        float ss = 0.f, sd = 0.f;
        for (int d = 0; d < DH; d++) {
            float w = lw[(size_t)k * C + h * DH + d];
            ss += w * as[h * DH + d];
            sd += w * ad[h * DH + d];
        }
        wsrc[wo + k * H + h] = ss;
        wdst[wo + k * H + h] = sd;
    }
    for (int j = 0; j < C; j++)
        lin16[lo16 + k * C + j] = (half_t)lw[(size_t)k * C + j];
    if (k == 0) {
        int co = (L == 0) ? 0 : (L == 1) ? 8 : 16;
        for (int w = 0; w < 2; w++)
            for (int h = 0; h < H; h++) {
                float s = 0.f;
                for (int d = 0; d < DH; d++)
                    s += ew[w * H * DH + h * DH + d] * ae[h * DH + d];
                coef[co + w * H + h] = s;
            }
    }
}

// ---------------- a_src/a_dst directly from h: one thread per node ----------------

template <int H>
__global__ void k_att_h(const float* __restrict__ h, const float* __restrict__ wsrc,
                        const float* __restrict__ wdst,
                        float* __restrict__ a_src, float* __restrict__ a_dst) {
    int n = blockIdx.x * blockDim.x + threadIdx.x;
    if (n >= NN) return;
    float as[H], ad[H];
#pragma unroll
    for (int hh = 0; hh < H; hh++) { as[hh] = 0.f; ad[hh] = 0.f; }
    const float* hr = h + (size_t)n * DH;
    for (int k = 0; k < DH; k++) {
        float hv = hr[k];
#pragma unroll
        for (int hh = 0; hh < H; hh++) {
            as[hh] += hv * wsrc[k * H + hh];
            ad[hh] += hv * wdst[k * H + hh];
        }
    }
#pragma unroll
    for (int hh = 0; hh < H; hh++) {
        a_src[n * H + hh] = as[hh];
        a_dst[n * H + hh] = ad[hh];
    }
}

// ---------------- per-node den + normalized alpha (fp16): one THREAD per node ----------------

template <int H>
__global__ void k_mden(const int* __restrict__ row, const int4* __restrict__ csr,
                       const float* __restrict__ a_src, const float* __restrict__ a_dst,
                       const float* __restrict__ coef, half_t* __restrict__ abuf) {
    int n = blockIdx.x * blockDim.x + threadIdx.x;
    if (n >= NN) return;
    int r0 = row[n], r1 = row[n + 1];
    float ad[H], cf[2 * H], den[H];
#pragma unroll
    for (int h = 0; h < H; h++) { ad[h] = a_dst[n * H + h]; den[h] = 0.f; }
#pragma unroll
    for (int i = 0; i < 2 * H; i++) cf[i] = coef[i];
    for (int j = r0; j < r1; j++) {
        int4 rec = csr[j];
        int s = rec.x;
        float e0 = __int_as_float(rec.y), e1 = __int_as_float(rec.z);
#pragma unroll
        for (int h = 0; h < H; h++) {
            float lg = a_src[s * H + h] + ad[h] + e0 * cf[h] + e1 * cf[H + h];
            lg = (lg > 0.f) ? lg : 0.2f * lg;
            den[h] += __expf(lg);
        }
    }
    float inv[H];
#pragma unroll
    for (int h = 0; h < H; h++) inv[h] = 1.f / (den[h] + 1e-16f);
    for (int j = r0; j < r1; j++) {
        int4 rec = csr[j];
        int s = rec.x;
        float e0 = __int_as_float(rec.y), e1 = __int_as_float(rec.z);
        half_t a4[H];
#pragma unroll
        for (int h = 0; h < H; h++) {
            float lg = a_src[s * H + h] + ad[h] + e0 * cf[h] + e1 * cf[H + h];
            lg = (lg > 0.f) ? lg : 0.2f * lg;
            a4[h] = (half_t)(__expf(lg) * inv[h]);
        }
        if constexpr (H == 4) {
            *(float2*)(abuf + (size_t)j * 4) = *(float2*)a4;
        } else {
            abuf[j] = a4[0];
        }
    }
}

// ---------------- aggregate on h: one WAVE per node, lane = k, 4-edge pipelined ----------------

template <int H>
__global__ void k_agg_h(const int* __restrict__ row, const int4* __restrict__ csr,
                        const half_t* __restrict__ abuf, const half_t* __restrict__ h16,
                        half_t* __restrict__ agg) {
    int gid = blockIdx.x * blockDim.x + threadIdx.x;
    int n = gid >> 6;
    int lane = gid & 63;
    if (n >= NN) return;
    int r0 = row[n], r1 = row[n + 1];
    float acc[H];
#pragma unroll
    for (int h = 0; h < H; h++) acc[h] = 0.f;
    int j = r0;
    for (; j + 4 <= r1; j += 4) {
        int s0 = csr[j].x, s1 = csr[j + 1].x, s2 = csr[j + 2].x, s3 = csr[j + 3].x;
        float av[4][H];
        if constexpr (H == 4) {
            float2 r0v = *(const float2*)(abuf + (size_t)(j + 0) * 4);
            float2 r1v = *(const float2*)(abuf + (size_t)(j + 1) * 4);
            float2 r2v = *(const float2*)(abuf + (size_t)(j + 2) * 4);
            float2 r3v = *(const float2*)(abuf + (size_t)(j + 3) * 4);
            const half_t* p0 = (const half_t*)&r0v;
            const half_t* p1 = (const half_t*)&r1v;
            const half_t* p2 = (const half_t*)&r2v;
            const half_t* p3 = (const half_t*)&r3v;
#pragma unroll
            for (int h = 0; h < 4; h++) {
                av[0][h] = (float)p0[h]; av[1][h] = (float)p1[h];
                av[2][h] = (float)p2[h]; av[3][h] = (float)p3[h];
            }
        } else {
            av[0][0] = (float)abuf[j];     av[1][0] = (float)abuf[j + 1];
            av[2][0] = (float)abuf[j + 2]; av[3][0] = (float)abuf[j + 3];
        }
        float hv0 = (float)h16[(size_t)s0 * DH + lane];
        float hv1 = (float)h16[(size_t)s1 * DH + lane];
        float hv2 = (float)h16[(size_t)s2 * DH + lane];
        float hv3 = (float)h16[(size_t)s3 * DH + lane];
#pragma unroll
        for (int h = 0; h < H; h++) acc[h] += av[0][h] * hv0;
#pragma unroll
        for (int h = 0; h < H; h++) acc[h] += av[1][h] * hv1;
#pragma unroll
        for (int h = 0; h < H; h++) acc[h] += av[2][h] * hv2;
#pragma unroll
        for (int h = 0; h < H; h++) acc[h] += av[3][h] * hv3;
    }
    for (; j < r1; j++) {
        int s = csr[j].x;
        float av[H];
        if constexpr (H == 4) {
            float2 raw = *(const float2*)(abuf + (size_t)j * 4);
            const half_t* ap = (const half_t*)&raw;
#pragma unroll
            for (int h = 0; h < H; h++) av[h] = (float)ap[h];
        } else {
            av[0] = (float)abuf[j];
        }
        float hv = (float)h16[(size_t)s * DH + lane];
#pragma unroll
        for (int h = 0; h < H; h++) acc[h] += av[h] * hv;
    }
#pragma unroll
    for (int h = 0; h < H; h++)
        agg[(size_t)n * (H * DH) + h * DH + lane] = (half_t)acc[h];
}

// ---------------- out = mean_h(agg_h @ W16_h) + bias, relu, +res; 4 nodes x 8 cols ----------------
// fp16 W + fp16 agg, float4 loads carrying 8 halves: 384 load-instrs/thread (was 768).
// f32 accumulate, k-ascending order per (h).

template <int H>
__global__ void k_out(const half_t* __restrict__ agg, const half_t* __restrict__ lw16,
                      const float* __restrict__ bias, const float* __restrict__ hin,
                      float* __restrict__ hout, half_t* __restrict__ h16out) {
    constexpr int C = H * DH;
    constexpr int TPN = DH / 8;                // 8 threads per 4-node group
    int gid = blockIdx.x * blockDim.x + threadIdx.x;
    int nb = gid / TPN;
    int c0 = (gid % TPN) * 8;
    if (nb >= NN / 4) return;
    int n0 = nb * 4;
    float acc[4][8];
#pragma unroll
    for (int i = 0; i < 4; i++)
#pragma unroll
        for (int j = 0; j < 8; j++) acc[i][j] = 0.f;
#pragma unroll
    for (int h = 0; h < H; h++) {
        for (int q8 = 0; q8 < DH / 8; q8++) {
            float areg[4][8];
#pragma unroll
            for (int i = 0; i < 4; i++) {
                float4 raw = *(const float4*)(agg + (size_t)(n0 + i) * C + h * DH + q8 * 8);
                const half_t* ap = (const half_t*)&raw;
#pragma unroll
                for (int t = 0; t < 8; t++) areg[i][t] = (float)ap[t];
            }
#pragma unroll
            for (int t = 0; t < 8; t++) {
                int k = q8 * 8 + t;
                float4 wraw = *(const float4*)(lw16 + (size_t)k * C + h * DH + c0);
                const half_t* wp = (const half_t*)&wraw;
                float wv[8];
#pragma unroll
                for (int j = 0; j < 8; j++) wv[j] = (float)wp[j];
#pragma unroll
                for (int i = 0; i < 4; i++) {
                    float av = areg[i][t];
#pragma unroll
                    for (int j = 0; j < 8; j++) acc[i][j] += av * wv[j];
                }
            }
        }
    }
    float bv[8];
#pragma unroll
    for (int j = 0; j < 8; j++) bv[j] = bias[c0 + j];
#pragma unroll
    for (int i = 0; i < 4; i++) {
        const float* rp = hin + (size_t)(n0 + i) * DH + c0;
        float ov[8];
        half_t hv[8];
#pragma unroll
        for (int j = 0; j < 8; j++) {
            float v = acc[i][j] * (1.0f / H) + bv[j];
            v = fmaxf(v, 0.f) + rp[j];
            ov[j] = v;
            hv[j] = (half_t)v;
        }
        float* op = hout + (size_t)(n0 + i) * DH + c0;
        *(float4*)(op)     = make_float4(ov[0], ov[1], ov[2], ov[3]);
        *(float4*)(op + 4) = make_float4(ov[4], ov[5], ov[6], ov[7]);
        *(float4*)(h16out + (size_t)(n0 + i) * DH + c0) = *(float4*)hv;
    }
}

// ---------------- final MLP head ----------------

__global__ void k_head_s(const float* __restrict__ h, const float* __restrict__ fc1_W,
                         const float* __restrict__ fc1_b, const float* __restrict__ fc2_W,
                         const float* __restrict__ fc2_b, float* __restrict__ out) {
    int n = blockIdx.x * blockDim.x + threadIdx.x;
    if (n >= NN) return;
    float y[32];
#pragma unroll
    for (int c = 0; c < 32; c++) y[c] = fc1_b[c];
    for (int k = 0; k < DH; k++) {
        float hk = h[n * DH + k];
#pragma unroll
        for (int c = 0; c < 32; c++) y[c] += hk * fc1_W[k * 32 + c];
    }
    float o0 = fc2_b[0], o1 = fc2_b[1];
#pragma unroll
    for (int c = 0; c < 32; c++) {
        float yr = fmaxf(y[c], 0.f);
        o0 += yr * fc2_W[c * 2];
        o1 += yr * fc2_W[c * 2 + 1];
    }
    out[2 * n] = tanhf(o0);
    out[2 * n + 1] = tanhf(o1);
}

// ---------------- launch ----------------

extern "C" void kernel_launch(void* const* d_in, const int* in_sizes, int n_in,
                              void* d_out, int out_size, void* d_ws, size_t ws_size,
                              hipStream_t stream) {
    const float* x     = (const float*)d_in[0];
    const int*   ei    = (const int*)d_in[1];
    const float* ea    = (const float*)d_in[2];
    const float* enc_W = (const float*)d_in[3];
    const float* enc_b = (const float*)d_in[4];
    const float* lin_W[3]    = {(const float*)d_in[5],  (const float*)d_in[11], (const float*)d_in[17]};
    const float* att_src[3]  = {(const float*)d_in[6],  (const float*)d_in[12], (const float*)d_in[18]};
    const float* att_dst[3]  = {(const float*)d_in[7],  (const float*)d_in[13], (const float*)d_in[19]};
    const float* edge_W[3]   = {(const float*)d_in[8],  (const float*)d_in[14], (const float*)d_in[20]};
    const float* att_edge[3] = {(const float*)d_in[9],  (const float*)d_in[15], (const float*)d_in[21]};
    const float* bias[3]     = {(const float*)d_in[10], (const float*)d_in[16], (const float*)d_in[22]};
    const float* fc1_W = (const float*)d_in[23];
    const float* fc1_b = (const float*)d_in[24];
    const float* fc2_W = (const float*)d_in[25];
    const float* fc2_b = (const float*)d_in[26];
    float* out = (float*)d_out;

    char* p = (char*)d_ws;
    auto alloc = [&](size_t bytes) -> void* {
        void* r = (void*)p;
        p += (bytes + 255) & ~(size_t)255;
        return r;
    };
    int*    deg    = (int*)alloc((size_t)NN * 4);
    int*    part   = (int*)alloc((size_t)NCHUNK * 4);
    int*    row    = (int*)alloc((size_t)(NN + 1) * 4);
    int*    cursor = (int*)alloc((size_t)NN * 4);
    int4*   csr    = (int4*)alloc((size_t)ETOT * 16);
    float*  a_srcB = (float*)alloc((size_t)NN * 4 * 4);
    float*  a_dstB = (float*)alloc((size_t)NN * 4 * 4);
    float*  wsrcA  = (float*)alloc(576 * 4);
    float*  wdstA  = (float*)alloc(576 * 4);
    float*  coefA  = (float*)alloc(18 * 4);
    half_t* lin16  = (half_t*)alloc((size_t)(16384 * 2 + 4096) * 2);
    half_t* abuf   = (half_t*)alloc((size_t)ETOT * 4 * 2);
    half_t* aggB   = (half_t*)alloc((size_t)NN * 256 * 2);
    half_t* h16    = (half_t*)alloc((size_t)NN * DH * 2);
    float*  hA     = (float*)alloc((size_t)NN * DH * 4);
    float*  hB     = (float*)alloc((size_t)NN * DH * 4);

    const int BT = 256;
    const int nodeBlocks  = (NN + BT - 1) / BT;
    const int edgeBlocks  = (NE + BT - 1) / BT;
    const int chunkBlocks = (NCHUNK + BT - 1) / BT;
    const int ndBlocks    = (NN * DH + BT - 1) / BT;
    const int nodeWaveBlocks = (NN * 64 + BT - 1) / BT;
    const int outBlocks   = ((NN / 4) * (DH / 8) + BT - 1) / BT;   // 8-col threads

    k_zero_init<<<nodeBlocks, BT, 0, stream>>>(deg);
    k_deg<<<edgeBlocks, BT, 0, stream>>>(ei, deg);
    k_scan_a<<<chunkBlocks, BT, 0, stream>>>(deg, part);
    k_scan_b<<<1, 64, 0, stream>>>(part);
    k_scan_c<<<chunkBlocks, BT, 0, stream>>>(deg, part, row, cursor);
    k_fill_csr<<<edgeBlocks, BT, 0, stream>>>(ei, ea, cursor, csr);
    k_fill_self<<<nodeBlocks, BT, 0, stream>>>(deg, row, csr);
    k_encoder<<<ndBlocks, BT, 0, stream>>>(x, enc_W, enc_b, hA, h16);
    k_prep<<<3, 64, 0, stream>>>(lin_W[0], att_src[0], att_dst[0], edge_W[0], att_edge[0],
                                 lin_W[1], att_src[1], att_dst[1], edge_W[1], att_edge[1],
                                 lin_W[2], att_src[2], att_dst[2], edge_W[2], att_edge[2],
                                 wsrcA, wdstA, coefA, lin16);

    float* hin = hA;
    float* hout = hB;

    for (int L = 0; L < 3; L++) {
        const float* ws = wsrcA + ((L == 0) ? 0 : (L == 1) ? 256 : 512);
        const float* wd = wdstA + ((L == 0) ? 0 : (L == 1) ? 256 : 512);
        const float* cf = coefA + ((L == 0) ? 0 : (L == 1) ? 8 : 16);
        const half_t* lw16 = lin16 + ((L == 0) ? 0 : (L == 1) ? 16384 : 32768);
        if (L < 2) {
            constexpr int H = 4;
            k_att_h<H><<<nodeBlocks, BT, 0, stream>>>(hin, ws, wd, a_srcB, a_dstB);
            k_mden<H><<<nodeBlocks, BT, 0, stream>>>(row, csr, a_srcB, a_dstB, cf, abuf);
            k_agg_h<H><<<nodeWaveBlocks, BT, 0, stream>>>(row, csr, abuf, h16, aggB);
            k_out<H><<<outBlocks, BT, 0, stream>>>(aggB, lw16, bias[L], hin, hout, h16);
        } else {
            constexpr int H = 1;
            k_att_h<H><<<nodeBlocks, BT, 0, stream>>>(hin, ws, wd, a_srcB, a_dstB);
            k_mden<H><<<nodeBlocks, BT, 0, stream>>>(row, csr, a_srcB, a_dstB, cf, abuf);
            k_agg_h<H><<<nodeWaveBlocks, BT, 0, stream>>>(row, csr, abuf, h16, aggB);
            k_out<H><<<outBlocks, BT, 0, stream>>>(aggB, lw16, bias[L], hin, hout, h16);
        }
        float* t = hin; hin = hout; hout = t;
    }
    k_head_s<<<nodeBlocks, BT, 0, stream>>>(hin, fc1_W, fc1_b, fc2_W, fc2_b, out);
}

// Round 14
// 663.404 us; speedup vs baseline: 1.2345x; 1.1234x over previous
//
#include <hip/hip_runtime.h>
#include <math.h>

#define NN 100000
#define NE 1000000
#define DH 64
constexpr int ETOT = NE + NN;
constexpr int CHUNK = 100;
constexpr int NCHUNK = (NN + CHUNK - 1) / CHUNK;   // 1000

typedef _Float16 half_t;
typedef _Float16 f16x8 __attribute__((ext_vector_type(8)));
typedef float f32x4 __attribute__((ext_vector_type(4)));

// AoS edge record: {int src; float e0; float e1; int pad} stored as int4

// ---------------- degree ----------------

__global__ void k_zero_init(int* __restrict__ deg) {
    int i = blockIdx.x * blockDim.x + threadIdx.x;
    if (i < NN) deg[i] = 0;
}

__global__ void k_deg(const int* __restrict__ ei, int* __restrict__ deg) {
    int e = blockIdx.x * blockDim.x + threadIdx.x;
    if (e < NE) atomicAdd(&deg[ei[NE + e]], 1);
}

// ---------------- chunked prefix scan (scalar) ----------------

__global__ void k_scan_a(const int* __restrict__ deg, int* __restrict__ part) {
    int c = blockIdx.x * blockDim.x + threadIdx.x;
    if (c >= NCHUNK) return;
    int lo = c * CHUNK;
    int hi = lo + CHUNK; if (hi > NN) hi = NN;
    int s = 0;
    for (int i = lo; i < hi; i++) s += deg[i];
    part[c] = s;
}

__global__ void k_scan_b(int* __restrict__ part) {
    if (threadIdx.x || blockIdx.x) return;
    int run = 0;
    for (int i = 0; i < NCHUNK; i++) { int t = part[i]; part[i] = run; run += t; }
}

__global__ void k_scan_c(const int* __restrict__ deg, const int* __restrict__ part,
                         int* __restrict__ row, int* __restrict__ cursor) {
    int c = blockIdx.x * blockDim.x + threadIdx.x;
    if (c >= NCHUNK) return;
    int lo = c * CHUNK;
    int hi = lo + CHUNK; if (hi > NN) hi = NN;
    int run = part[c];
    for (int i = lo; i < hi; i++) {
        int r = run + i;
        row[i] = r;
        cursor[i] = r;
        run += deg[i];
    }
    if (c == NCHUNK - 1) row[NN] = run + NN;
}

__global__ void k_fill_csr(const int* __restrict__ ei, const float* __restrict__ ea,
                           int* __restrict__ cursor, int4* __restrict__ csr) {
    int e = blockIdx.x * blockDim.x + threadIdx.x;
    if (e < NE) {
        int s = ei[e];
        int d = ei[NE + e];
        int pos = atomicAdd(&cursor[d], 1);
        int4 rec;
        rec.x = s;
        rec.y = __float_as_int(ea[2 * e]);
        rec.z = __float_as_int(ea[2 * e + 1]);
        rec.w = 0;
        csr[pos] = rec;
    }
}

__global__ void k_fill_self(const int* __restrict__ deg, const int* __restrict__ row,
                            int4* __restrict__ csr) {
    int n = blockIdx.x * blockDim.x + threadIdx.x;
    if (n >= NN) return;
    int r0 = row[n];
    int dg = deg[n];
    float s0 = 0.f, s1 = 0.f;
    for (int j = r0; j < r0 + dg; j++) {
        int4 rec = csr[j];
        s0 += __int_as_float(rec.y);
        s1 += __int_as_float(rec.z);
    }
    float dv = fmaxf((float)dg, 1.0f);
    int4 self;
    self.x = n;
    self.y = __float_as_int(s0 / dv);
    self.z = __float_as_int(s1 / dv);
    self.w = 0;
    csr[r0 + dg] = self;
}

// ---------------- encoder: h = relu(x @ enc_W + enc_b), writes f32 + fp16 ----------------

__global__ void k_encoder(const float* __restrict__ x, const float* __restrict__ W,
                          const float* __restrict__ b, float* __restrict__ h,
                          half_t* __restrict__ h16) {
    int idx = blockIdx.x * blockDim.x + threadIdx.x;
    int n = idx >> 6, d = idx & 63;
    if (n < NN) {
        float v = x[2 * n] * W[d] + x[2 * n + 1] * W[DH + d] + b[d];
        v = fmaxf(v, 0.f);
        h[idx] = v;
        h16[idx] = (half_t)v;
    }
}

// ---------------- fused prep (all 3 layers): wsrc/wdst, coef, and MFMA B-operand Wt ------------
// wsrc/wdst: L0 [0,256), L1 [256,512), L2 [512,576). coef: L0 [0,8), L1 [8,16), L2 [16,18).
// Wt (fp16): Wt_L[j][c] = lin_W[c&63][(c>>6)*64 + j]  (j<64, c<C) — head-stacked, transposed.
// Offsets: L0 at 0 (64x256), L1 at 16384 (64x256), L2 at 32768 (64x64).

__global__ void k_prep(const float* __restrict__ lw0, const float* __restrict__ as0,
                       const float* __restrict__ ad0, const float* __restrict__ ew0,
                       const float* __restrict__ ae0,
                       const float* __restrict__ lw1, const float* __restrict__ as1,
                       const float* __restrict__ ad1, const float* __restrict__ ew1,
                       const float* __restrict__ ae1,
                       const float* __restrict__ lw2, const float* __restrict__ as2,
                       const float* __restrict__ ad2, const float* __restrict__ ew2,
                       const float* __restrict__ ae2,
                       float* __restrict__ wsrc, float* __restrict__ wdst,
                       float* __restrict__ coef, half_t* __restrict__ wt) {
    int L = blockIdx.x;
    int k = threadIdx.x;
    if (k >= DH) return;
    const float* lw = (L == 0) ? lw0 : (L == 1) ? lw1 : lw2;
    const float* as = (L == 0) ? as0 : (L == 1) ? as1 : as2;
    const float* ad = (L == 0) ? ad0 : (L == 1) ? ad1 : ad2;
    const float* ew = (L == 0) ? ew0 : (L == 1) ? ew1 : ew2;
    const float* ae = (L == 0) ? ae0 : (L == 1) ? ae1 : ae2;
    int H = (L < 2) ? 4 : 1;
    int C = H * DH;
    int wo = (L == 0) ? 0 : (L == 1) ? 256 : 512;
    int wto = (L == 0) ? 0 : (L == 1) ? 16384 : 32768;
    for (int h = 0; h < H; h++) {
        float ss = 0.f, sd = 0.f;
        for (int d = 0; d < DH; d++) {
            float w = lw[(size_t)k * C + h * DH + d];
            ss += w * as[h * DH + d];
            sd += w * ad[h * DH + d];
        }
        wsrc[wo + k * H + h] = ss;
        wdst[wo + k * H + h] = sd;
    }
    // Wt row j = k
    for (int c = 0; c < C; c++)
        wt[wto + k * C + c] = (half_t)lw[(size_t)(c & 63) * C + (c >> 6) * 64 + k];
    if (k == 0) {
        int co = (L == 0) ? 0 : (L == 1) ? 8 : 16;
        for (int w = 0; w < 2; w++)
            for (int h = 0; h < H; h++) {
                float s = 0.f;
                for (int d = 0; d < DH; d++)
                    s += ew[w * H * DH + h * DH + d] * ae[h * DH + d];
                coef[co + w * H + h] = s;
            }
    }
}

// ---------------- a_src/a_dst directly from h: one thread per node ----------------

template <int H>
__global__ void k_att_h(const float* __restrict__ h, const float* __restrict__ wsrc,
                        const float* __restrict__ wdst,
                        float* __restrict__ a_src, float* __restrict__ a_dst) {
    int n = blockIdx.x * blockDim.x + threadIdx.x;
    if (n >= NN) return;
    float as[H], ad[H];
#pragma unroll
    for (int hh = 0; hh < H; hh++) { as[hh] = 0.f; ad[hh] = 0.f; }
    const float* hr = h + (size_t)n * DH;
    for (int k = 0; k < DH; k++) {
        float hv = hr[k];
#pragma unroll
        for (int hh = 0; hh < H; hh++) {
            as[hh] += hv * wsrc[k * H + hh];
            ad[hh] += hv * wdst[k * H + hh];
        }
    }
#pragma unroll
    for (int hh = 0; hh < H; hh++) {
        a_src[n * H + hh] = as[hh];
        a_dst[n * H + hh] = ad[hh];
    }
}

// ---------------- per-node den + normalized alpha (fp16): one THREAD per node ----------------

template <int H>
__global__ void k_mden(const int* __restrict__ row, const int4* __restrict__ csr,
                       const float* __restrict__ a_src, const float* __restrict__ a_dst,
                       const float* __restrict__ coef, half_t* __restrict__ abuf) {
    int n = blockIdx.x * blockDim.x + threadIdx.x;
    if (n >= NN) return;
    int r0 = row[n], r1 = row[n + 1];
    float ad[H], cf[2 * H], den[H];
#pragma unroll
    for (int h = 0; h < H; h++) { ad[h] = a_dst[n * H + h]; den[h] = 0.f; }
#pragma unroll
    for (int i = 0; i < 2 * H; i++) cf[i] = coef[i];
    for (int j = r0; j < r1; j++) {
        int4 rec = csr[j];
        int s = rec.x;
        float e0 = __int_as_float(rec.y), e1 = __int_as_float(rec.z);
#pragma unroll
        for (int h = 0; h < H; h++) {
            float lg = a_src[s * H + h] + ad[h] + e0 * cf[h] + e1 * cf[H + h];
            lg = (lg > 0.f) ? lg : 0.2f * lg;
            den[h] += __expf(lg);
        }
    }
    float inv[H];
#pragma unroll
    for (int h = 0; h < H; h++) inv[h] = 1.f / (den[h] + 1e-16f);
    for (int j = r0; j < r1; j++) {
        int4 rec = csr[j];
        int s = rec.x;
        float e0 = __int_as_float(rec.y), e1 = __int_as_float(rec.z);
        half_t a4[H];
#pragma unroll
        for (int h = 0; h < H; h++) {
            float lg = a_src[s * H + h] + ad[h] + e0 * cf[h] + e1 * cf[H + h];
            lg = (lg > 0.f) ? lg : 0.2f * lg;
            a4[h] = (half_t)(__expf(lg) * inv[h]);
        }
        if constexpr (H == 4) {
            *(float2*)(abuf + (size_t)j * 4) = *(float2*)a4;
        } else {
            abuf[j] = a4[0];
        }
    }
}

// ---------------- aggregate on h: one WAVE per node, lane = k, 4-edge pipelined ----------------

template <int H>
__global__ void k_agg_h(const int* __restrict__ row, const int4* __restrict__ csr,
                        const half_t* __restrict__ abuf, const half_t* __restrict__ h16,
                        half_t* __restrict__ agg) {
    int gid = blockIdx.x * blockDim.x + threadIdx.x;
    int n = gid >> 6;
    int lane = gid & 63;
    if (n >= NN) return;
    int r0 = row[n], r1 = row[n + 1];
    float acc[H];
#pragma unroll
    for (int h = 0; h < H; h++) acc[h] = 0.f;
    int j = r0;
    for (; j + 4 <= r1; j += 4) {
        int s0 = csr[j].x, s1 = csr[j + 1].x, s2 = csr[j + 2].x, s3 = csr[j + 3].x;
        float av[4][H];
        if constexpr (H == 4) {
            float2 r0v = *(const float2*)(abuf + (size_t)(j + 0) * 4);
            float2 r1v = *(const float2*)(abuf + (size_t)(j + 1) * 4);
            float2 r2v = *(const float2*)(abuf + (size_t)(j + 2) * 4);
            float2 r3v = *(const float2*)(abuf + (size_t)(j + 3) * 4);
            const half_t* p0 = (const half_t*)&r0v;
            const half_t* p1 = (const half_t*)&r1v;
            const half_t* p2 = (const half_t*)&r2v;
            const half_t* p3 = (const half_t*)&r3v;
#pragma unroll
            for (int h = 0; h < 4; h++) {
                av[0][h] = (float)p0[h]; av[1][h] = (float)p1[h];
                av[2][h] = (float)p2[h]; av[3][h] = (float)p3[h];
            }
        } else {
            av[0][0] = (float)abuf[j];     av[1][0] = (float)abuf[j + 1];
            av[2][0] = (float)abuf[j + 2]; av[3][0] = (float)abuf[j + 3];
        }
        float hv0 = (float)h16[(size_t)s0 * DH + lane];
        float hv1 = (float)h16[(size_t)s1 * DH + lane];
        float hv2 = (float)h16[(size_t)s2 * DH + lane];
        float hv3 = (float)h16[(size_t)s3 * DH + lane];
#pragma unroll
        for (int h = 0; h < H; h++) acc[h] += av[0][h] * hv0;
#pragma unroll
        for (int h = 0; h < H; h++) acc[h] += av[1][h] * hv1;
#pragma unroll
        for (int h = 0; h < H; h++) acc[h] += av[2][h] * hv2;
#pragma unroll
        for (int h = 0; h < H; h++) acc[h] += av[3][h] * hv3;
    }
    for (; j < r1; j++) {
        int s = csr[j].x;
        float av[H];
        if constexpr (H == 4) {
            float2 raw = *(const float2*)(abuf + (size_t)j * 4);
            const half_t* ap = (const half_t*)&raw;
#pragma unroll
            for (int h = 0; h < H; h++) av[h] = (float)ap[h];
        } else {
            av[0] = (float)abuf[j];
        }
        float hv = (float)h16[(size_t)s * DH + lane];
#pragma unroll
        for (int h = 0; h < H; h++) acc[h] += av[h] * hv;
    }
#pragma unroll
    for (int h = 0; h < H; h++)
        agg[(size_t)n * (H * DH) + h * DH + lane] = (half_t)acc[h];
}

// ---------------- out via MFMA: D[16n x 64j] = agg[16n x C] * Wt^T[C x 64] ----------------
// A-frag: lane holds agg[n0+(l&15)][ks*32 + (l>>4)*8 + i]  (16B coalesced, reused over j-tiles)
// B-frag: lane holds Wt[ct*16+(l&15)][ks*32 + (l>>4)*8 + i] (Wt[j][c] built in k_prep)
// D: lane holds D[(l>>4)*4 + i][ct*16 + (l&15)]  (m89-verified mapping)

template <int H>
__global__ void k_out_mfma(const half_t* __restrict__ agg, const half_t* __restrict__ wt,
                           const float* __restrict__ bias, const float* __restrict__ hin,
                           float* __restrict__ hout, half_t* __restrict__ h16out) {
    constexpr int C = H * DH;
    constexpr int KS = C / 32;                 // MFMA K-steps: 8 (H=4) or 2 (H=1)
    int gid = blockIdx.x * blockDim.x + threadIdx.x;
    int wave = gid >> 6;
    int lane = gid & 63;
    if (wave >= NN / 16) return;
    int n0 = wave * 16;
    int r  = lane & 15;
    int kb = lane >> 4;

    f16x8 afrag[KS];
#pragma unroll
    for (int s = 0; s < KS; s++)
        afrag[s] = *(const f16x8*)(agg + (size_t)(n0 + r) * C + s * 32 + kb * 8);

#pragma unroll
    for (int ct = 0; ct < 4; ct++) {
        f32x4 acc = {0.f, 0.f, 0.f, 0.f};
#pragma unroll
        for (int s = 0; s < KS; s++) {
            f16x8 bfrag = *(const f16x8*)(wt + (size_t)(ct * 16 + r) * C + s * 32 + kb * 8);
            acc = __builtin_amdgcn_mfma_f32_16x16x32_f16(afrag[s], bfrag, acc, 0, 0, 0);
        }
        int j = ct * 16 + r;
        float bj = bias[j];
#pragma unroll
        for (int i = 0; i < 4; i++) {
            int n = n0 + kb * 4 + i;
            float v = acc[i] * (1.0f / H) + bj;
            v = fmaxf(v, 0.f) + hin[(size_t)n * DH + j];
            hout[(size_t)n * DH + j] = v;
            h16out[(size_t)n * DH + j] = (half_t)v;
        }
    }
}

// ---------------- final MLP head ----------------

__global__ void k_head_s(const float* __restrict__ h, const float* __restrict__ fc1_W,
                         const float* __restrict__ fc1_b, const float* __restrict__ fc2_W,
                         const float* __restrict__ fc2_b, float* __restrict__ out) {
    int n = blockIdx.x * blockDim.x + threadIdx.x;
    if (n >= NN) return;
    float y[32];
#pragma unroll
    for (int c = 0; c < 32; c++) y[c] = fc1_b[c];
    for (int k = 0; k < DH; k++) {
        float hk = h[n * DH + k];
#pragma unroll
        for (int c = 0; c < 32; c++) y[c] += hk * fc1_W[k * 32 + c];
    }
    float o0 = fc2_b[0], o1 = fc2_b[1];
#pragma unroll
    for (int c = 0; c < 32; c++) {
        float yr = fmaxf(y[c], 0.f);
        o0 += yr * fc2_W[c * 2];
        o1 += yr * fc2_W[c * 2 + 1];
    }
    out[2 * n] = tanhf(o0);
    out[2 * n + 1] = tanhf(o1);
}

// ---------------- launch ----------------

extern "C" void kernel_launch(void* const* d_in, const int* in_sizes, int n_in,
                              void* d_out, int out_size, void* d_ws, size_t ws_size,
                              hipStream_t stream) {
    const float* x     = (const float*)d_in[0];
    const int*   ei    = (const int*)d_in[1];
    const float* ea    = (const float*)d_in[2];
    const float* enc_W = (const float*)d_in[3];
    const float* enc_b = (const float*)d_in[4];
    const float* lin_W[3]    = {(const float*)d_in[5],  (const float*)d_in[11], (const float*)d_in[17]};
    const float* att_src[3]  = {(const float*)d_in[6],  (const float*)d_in[12], (const float*)d_in[18]};
    const float* att_dst[3]  = {(const float*)d_in[7],  (const float*)d_in[13], (const float*)d_in[19]};
    const float* edge_W[3]   = {(const float*)d_in[8],  (const float*)d_in[14], (const float*)d_in[20]};
    const float* att_edge[3] = {(const float*)d_in[9],  (const float*)d_in[15], (const float*)d_in[21]};
    const float* bias[3]     = {(const float*)d_in[10], (const float*)d_in[16], (const float*)d_in[22]};
    const float* fc1_W = (const float*)d_in[23];
    const float* fc1_b = (const float*)d_in[24];
    const float* fc2_W = (const float*)d_in[25];
    const float* fc2_b = (const float*)d_in[26];
    float* out = (float*)d_out;

    char* p = (char*)d_ws;
    auto alloc = [&](size_t bytes) -> void* {
        void* r = (void*)p;
        p += (bytes + 255) & ~(size_t)255;
        return r;
    };
    int*    deg    = (int*)alloc((size_t)NN * 4);
    int*    part   = (int*)alloc((size_t)NCHUNK * 4);
    int*    row    = (int*)alloc((size_t)(NN + 1) * 4);
    int*    cursor = (int*)alloc((size_t)NN * 4);
    int4*   csr    = (int4*)alloc((size_t)ETOT * 16);
    float*  a_srcB = (float*)alloc((size_t)NN * 4 * 4);
    float*  a_dstB = (float*)alloc((size_t)NN * 4 * 4);
    float*  wsrcA  = (float*)alloc(576 * 4);
    float*  wdstA  = (float*)alloc(576 * 4);
    float*  coefA  = (float*)alloc(18 * 4);
    half_t* wtA    = (half_t*)alloc((size_t)(16384 * 2 + 4096) * 2);
    half_t* abuf   = (half_t*)alloc((size_t)ETOT * 4 * 2);
    half_t* aggB   = (half_t*)alloc((size_t)NN * 256 * 2);
    half_t* h16    = (half_t*)alloc((size_t)NN * DH * 2);
    float*  hA     = (float*)alloc((size_t)NN * DH * 4);
    float*  hB     = (float*)alloc((size_t)NN * DH * 4);

    const int BT = 256;
    const int nodeBlocks  = (NN + BT - 1) / BT;
    const int edgeBlocks  = (NE + BT - 1) / BT;
    const int chunkBlocks = (NCHUNK + BT - 1) / BT;
    const int ndBlocks    = (NN * DH + BT - 1) / BT;
    const int nodeWaveBlocks = (NN * 64 + BT - 1) / BT;
    const int mfmaBlocks  = ((NN / 16) * 64 + BT - 1) / BT;   // 6250 waves

    k_zero_init<<<nodeBlocks, BT, 0, stream>>>(deg);
    k_deg<<<edgeBlocks, BT, 0, stream>>>(ei, deg);
    k_scan_a<<<chunkBlocks, BT, 0, stream>>>(deg, part);
    k_scan_b<<<1, 64, 0, stream>>>(part);
    k_scan_c<<<chunkBlocks, BT, 0, stream>>>(deg, part, row, cursor);
    k_fill_csr<<<edgeBlocks, BT, 0, stream>>>(ei, ea, cursor, csr);
    k_fill_self<<<nodeBlocks, BT, 0, stream>>>(deg, row, csr);
    k_encoder<<<ndBlocks, BT, 0, stream>>>(x, enc_W, enc_b, hA, h16);
    k_prep<<<3, 64, 0, stream>>>(lin_W[0], att_src[0], att_dst[0], edge_W[0], att_edge[0],
                                 lin_W[1], att_src[1], att_dst[1], edge_W[1], att_edge[1],
                                 lin_W[2], att_src[2], att_dst[2], edge_W[2], att_edge[2],
                                 wsrcA, wdstA, coefA, wtA);

    float* hin = hA;
    float* hout = hB;

    for (int L = 0; L < 3; L++) {
        const float* ws = wsrcA + ((L == 0) ? 0 : (L == 1) ? 256 : 512);
        const float* wd = wdstA + ((L == 0) ? 0 : (L == 1) ? 256 : 512);
        const float* cf = coefA + ((L == 0) ? 0 : (L == 1) ? 8 : 16);
        const half_t* wt = wtA + ((L == 0) ? 0 : (L == 1) ? 16384 : 32768);
        if (L < 2) {
            constexpr int H = 4;
            k_att_h<H><<<nodeBlocks, BT, 0, stream>>>(hin, ws, wd, a_srcB, a_dstB);
            k_mden<H><<<nodeBlocks, BT, 0, stream>>>(row, csr, a_srcB, a_dstB, cf, abuf);
            k_agg_h<H><<<nodeWaveBlocks, BT, 0, stream>>>(row, csr, abuf, h16, aggB);
            k_out_mfma<H><<<mfmaBlocks, BT, 0, stream>>>(aggB, wt, bias[L], hin, hout, h16);
        } else {
            constexpr int H = 1;
            k_att_h<H><<<nodeBlocks, BT, 0, stream>>>(hin, ws, wd, a_srcB, a_dstB);
            k_mden<H><<<nodeBlocks, BT, 0, stream>>>(row, csr, a_srcB, a_dstB, cf, abuf);
            k_agg_h<H><<<nodeWaveBlocks, BT, 0, stream>>>(row, csr, abuf, h16, aggB);
            k_out_mfma<H><<<mfmaBlocks, BT, 0, stream>>>(aggB, wt, bias[L], hin, hout, h16);
        }
        float* t = hin; hin = hout; hout = t;
    }
    k_head_s<<<nodeBlocks, BT, 0, stream>>>(hin, fc1_W, fc1_b, fc2_W, fc2_b, out);
}

// Round 15
// 629.517 us; speedup vs baseline: 1.3009x; 1.0538x over previous
//
#include <hip/hip_runtime.h>
#include <math.h>

#define NN 100000
#define NE 1000000
#define DH 64
constexpr int ETOT = NE + NN;
constexpr int CHUNK = 100;
constexpr int NCHUNK = (NN + CHUNK - 1) / CHUNK;   // 1000

typedef _Float16 half_t;
typedef _Float16 f16x8 __attribute__((ext_vector_type(8)));
typedef float f32x4 __attribute__((ext_vector_type(4)));

// AoS edge record (8B): {int src; half2 ea} stored as int2

union h2u {
    int i;
    struct { unsigned short lo, hi; } u;
};
__device__ inline int pack_ea(float a, float b) {
    half_t ha = (half_t)a, hb = (half_t)b;
    h2u v;
    v.u.lo = *(unsigned short*)&ha;
    v.u.hi = *(unsigned short*)&hb;
    return v.i;
}
__device__ inline void unpack_ea(int p, float& a, float& b) {
    h2u v; v.i = p;
    half_t ha = *(half_t*)&v.u.lo;
    half_t hb = *(half_t*)&v.u.hi;
    a = (float)ha; b = (float)hb;
}

// ---------------- degree ----------------

__global__ void k_zero_init(int* __restrict__ deg) {
    int i = blockIdx.x * blockDim.x + threadIdx.x;
    if (i < NN) deg[i] = 0;
}

__global__ void k_deg(const int* __restrict__ ei, int* __restrict__ deg) {
    int e = blockIdx.x * blockDim.x + threadIdx.x;
    if (e < NE) atomicAdd(&deg[ei[NE + e]], 1);
}

// ---------------- chunked prefix scan (scalar) ----------------

__global__ void k_scan_a(const int* __restrict__ deg, int* __restrict__ part) {
    int c = blockIdx.x * blockDim.x + threadIdx.x;
    if (c >= NCHUNK) return;
    int lo = c * CHUNK;
    int hi = lo + CHUNK; if (hi > NN) hi = NN;
    int s = 0;
    for (int i = lo; i < hi; i++) s += deg[i];
    part[c] = s;
}

__global__ void k_scan_b(int* __restrict__ part) {
    if (threadIdx.x || blockIdx.x) return;
    int run = 0;
    for (int i = 0; i < NCHUNK; i++) { int t = part[i]; part[i] = run; run += t; }
}

__global__ void k_scan_c(const int* __restrict__ deg, const int* __restrict__ part,
                         int* __restrict__ row, int* __restrict__ cursor) {
    int c = blockIdx.x * blockDim.x + threadIdx.x;
    if (c >= NCHUNK) return;
    int lo = c * CHUNK;
    int hi = lo + CHUNK; if (hi > NN) hi = NN;
    int run = part[c];
    for (int i = lo; i < hi; i++) {
        int r = run + i;
        row[i] = r;
        cursor[i] = r;
        run += deg[i];
    }
    if (c == NCHUNK - 1) row[NN] = run + NN;
}

__global__ void k_fill_csr(const int* __restrict__ ei, const float* __restrict__ ea,
                           int* __restrict__ cursor, int2* __restrict__ csr) {
    int e = blockIdx.x * blockDim.x + threadIdx.x;
    if (e < NE) {
        int s = ei[e];
        int d = ei[NE + e];
        int pos = atomicAdd(&cursor[d], 1);
        int2 rec;
        rec.x = s;
        rec.y = pack_ea(ea[2 * e], ea[2 * e + 1]);
        csr[pos] = rec;
    }
}

__global__ void k_fill_self(const int* __restrict__ deg, const int* __restrict__ row,
                            int2* __restrict__ csr) {
    int n = blockIdx.x * blockDim.x + threadIdx.x;
    if (n >= NN) return;
    int r0 = row[n];
    int dg = deg[n];
    float s0 = 0.f, s1 = 0.f;
    for (int j = r0; j < r0 + dg; j++) {
        float e0, e1;
        unpack_ea(csr[j].y, e0, e1);
        s0 += e0; s1 += e1;
    }
    float dv = fmaxf((float)dg, 1.0f);
    int2 self;
    self.x = n;
    self.y = pack_ea(s0 / dv, s1 / dv);
    csr[r0 + dg] = self;
}

// ---------------- encoder: h = relu(x @ enc_W + enc_b), writes f32 + fp16 ----------------

__global__ void k_encoder(const float* __restrict__ x, const float* __restrict__ W,
                          const float* __restrict__ b, float* __restrict__ h,
                          half_t* __restrict__ h16) {
    int idx = blockIdx.x * blockDim.x + threadIdx.x;
    int n = idx >> 6, d = idx & 63;
    if (n < NN) {
        float v = x[2 * n] * W[d] + x[2 * n + 1] * W[DH + d] + b[d];
        v = fmaxf(v, 0.f);
        h[idx] = v;
        h16[idx] = (half_t)v;
    }
}

// ---------------- fused prep (all 3 layers): wsrc/wdst, coef, MFMA B-operand Wt ------------

__global__ void k_prep(const float* __restrict__ lw0, const float* __restrict__ as0,
                       const float* __restrict__ ad0, const float* __restrict__ ew0,
                       const float* __restrict__ ae0,
                       const float* __restrict__ lw1, const float* __restrict__ as1,
                       const float* __restrict__ ad1, const float* __restrict__ ew1,
                       const float* __restrict__ ae1,
                       const float* __restrict__ lw2, const float* __restrict__ as2,
                       const float* __restrict__ ad2, const float* __restrict__ ew2,
                       const float* __restrict__ ae2,
                       float* __restrict__ wsrc, float* __restrict__ wdst,
                       float* __restrict__ coef, half_t* __restrict__ wt) {
    int L = blockIdx.x;
    int k = threadIdx.x;
    if (k >= DH) return;
    const float* lw = (L == 0) ? lw0 : (L == 1) ? lw1 : lw2;
    const float* as = (L == 0) ? as0 : (L == 1) ? as1 : as2;
    const float* ad = (L == 0) ? ad0 : (L == 1) ? ad1 : ad2;
    const float* ew = (L == 0) ? ew0 : (L == 1) ? ew1 : ew2;
    const float* ae = (L == 0) ? ae0 : (L == 1) ? ae1 : ae2;
    int H = (L < 2) ? 4 : 1;
    int C = H * DH;
    int wo = (L == 0) ? 0 : (L == 1) ? 256 : 512;
    int wto = (L == 0) ? 0 : (L == 1) ? 16384 : 32768;
    for (int h = 0; h < H; h++) {
        float ss = 0.f, sd = 0.f;
        for (int d = 0; d < DH; d++) {
            float w = lw[(size_t)k * C + h * DH + d];
            ss += w * as[h * DH + d];
            sd += w * ad[h * DH + d];
        }
        wsrc[wo + k * H + h] = ss;
        wdst[wo + k * H + h] = sd;
    }
    for (int c = 0; c < C; c++)
        wt[wto + k * C + c] = (half_t)lw[(size_t)(c & 63) * C + (c >> 6) * 64 + k];
    if (k == 0) {
        int co = (L == 0) ? 0 : (L == 1) ? 8 : 16;
        for (int w = 0; w < 2; w++)
            for (int h = 0; h < H; h++) {
                float s = 0.f;
                for (int d = 0; d < DH; d++)
                    s += ew[w * H * DH + h * DH + d] * ae[h * DH + d];
                coef[co + w * H + h] = s;
            }
    }
}

// ---------------- a_src/a_dst directly from h: one thread per node ----------------

template <int H>
__global__ void k_att_h(const float* __restrict__ h, const float* __restrict__ wsrc,
                        const float* __restrict__ wdst,
                        float* __restrict__ a_src, float* __restrict__ a_dst) {
    int n = blockIdx.x * blockDim.x + threadIdx.x;
    if (n >= NN) return;
    float as[H], ad[H];
#pragma unroll
    for (int hh = 0; hh < H; hh++) { as[hh] = 0.f; ad[hh] = 0.f; }
    const float* hr = h + (size_t)n * DH;
    for (int k = 0; k < DH; k++) {
        float hv = hr[k];
#pragma unroll
        for (int hh = 0; hh < H; hh++) {
            as[hh] += hv * wsrc[k * H + hh];
            ad[hh] += hv * wdst[k * H + hh];
        }
    }
#pragma unroll
    for (int hh = 0; hh < H; hh++) {
        a_src[n * H + hh] = as[hh];
        a_dst[n * H + hh] = ad[hh];
    }
}

// ---------------- per-node den + normalized alpha (fp16): one THREAD per node ----------------

template <int H>
__global__ void k_mden(const int* __restrict__ row, const int2* __restrict__ csr,
                       const float* __restrict__ a_src, const float* __restrict__ a_dst,
                       const float* __restrict__ coef, half_t* __restrict__ abuf) {
    int n = blockIdx.x * blockDim.x + threadIdx.x;
    if (n >= NN) return;
    int r0 = row[n], r1 = row[n + 1];
    float ad[H], cf[2 * H], den[H];
#pragma unroll
    for (int h = 0; h < H; h++) { ad[h] = a_dst[n * H + h]; den[h] = 0.f; }
#pragma unroll
    for (int i = 0; i < 2 * H; i++) cf[i] = coef[i];
    for (int j = r0; j < r1; j++) {
        int2 rec = csr[j];
        int s = rec.x;
        float e0, e1;
        unpack_ea(rec.y, e0, e1);
#pragma unroll
        for (int h = 0; h < H; h++) {
            float lg = a_src[s * H + h] + ad[h] + e0 * cf[h] + e1 * cf[H + h];
            lg = (lg > 0.f) ? lg : 0.2f * lg;
            den[h] += __expf(lg);
        }
    }
    float inv[H];
#pragma unroll
    for (int h = 0; h < H; h++) inv[h] = 1.f / (den[h] + 1e-16f);
    for (int j = r0; j < r1; j++) {
        int2 rec = csr[j];
        int s = rec.x;
        float e0, e1;
        unpack_ea(rec.y, e0, e1);
        half_t a4[H];
#pragma unroll
        for (int h = 0; h < H; h++) {
            float lg = a_src[s * H + h] + ad[h] + e0 * cf[h] + e1 * cf[H + h];
            lg = (lg > 0.f) ? lg : 0.2f * lg;
            a4[h] = (half_t)(__expf(lg) * inv[h]);
        }
        if constexpr (H == 4) {
            *(float2*)(abuf + (size_t)j * 4) = *(float2*)a4;
        } else {
            abuf[j] = a4[0];
        }
    }
}

// ---------------- aggregate on h: one WAVE per node, lane = k, 4-edge pipelined ----------------

template <int H>
__global__ void k_agg_h(const int* __restrict__ row, const int2* __restrict__ csr,
                        const half_t* __restrict__ abuf, const half_t* __restrict__ h16,
                        half_t* __restrict__ agg) {
    int gid = blockIdx.x * blockDim.x + threadIdx.x;
    int n = gid >> 6;
    int lane = gid & 63;
    if (n >= NN) return;
    int r0 = row[n], r1 = row[n + 1];
    float acc[H];
#pragma unroll
    for (int h = 0; h < H; h++) acc[h] = 0.f;
    int j = r0;
    for (; j + 4 <= r1; j += 4) {
        int s0 = csr[j].x, s1 = csr[j + 1].x, s2 = csr[j + 2].x, s3 = csr[j + 3].x;
        float av[4][H];
        if constexpr (H == 4) {
            float2 r0v = *(const float2*)(abuf + (size_t)(j + 0) * 4);
            float2 r1v = *(const float2*)(abuf + (size_t)(j + 1) * 4);
            float2 r2v = *(const float2*)(abuf + (size_t)(j + 2) * 4);
            float2 r3v = *(const float2*)(abuf + (size_t)(j + 3) * 4);
            const half_t* p0 = (const half_t*)&r0v;
            const half_t* p1 = (const half_t*)&r1v;
            const half_t* p2 = (const half_t*)&r2v;
            const half_t* p3 = (const half_t*)&r3v;
#pragma unroll
            for (int h = 0; h < 4; h++) {
                av[0][h] = (float)p0[h]; av[1][h] = (float)p1[h];
                av[2][h] = (float)p2[h]; av[3][h] = (float)p3[h];
            }
        } else {
            av[0][0] = (float)abuf[j];     av[1][0] = (float)abuf[j + 1];
            av[2][0] = (float)abuf[j + 2]; av[3][0] = (float)abuf[j + 3];
        }
        float hv0 = (float)h16[(size_t)s0 * DH + lane];
        float hv1 = (float)h16[(size_t)s1 * DH + lane];
        float hv2 = (float)h16[(size_t)s2 * DH + lane];
        float hv3 = (float)h16[(size_t)s3 * DH + lane];
#pragma unroll
        for (int h = 0; h < H; h++) acc[h] += av[0][h] * hv0;
#pragma unroll
        for (int h = 0; h < H; h++) acc[h] += av[1][h] * hv1;
#pragma unroll
        for (int h = 0; h < H; h++) acc[h] += av[2][h] * hv2;
#pragma unroll
        for (int h = 0; h < H; h++) acc[h] += av[3][h] * hv3;
    }
    for (; j < r1; j++) {
        int s = csr[j].x;
        float av[H];
        if constexpr (H == 4) {
            float2 raw = *(const float2*)(abuf + (size_t)j * 4);
            const half_t* ap = (const half_t*)&raw;
#pragma unroll
            for (int h = 0; h < H; h++) av[h] = (float)ap[h];
        } else {
            av[0] = (float)abuf[j];
        }
        float hv = (float)h16[(size_t)s * DH + lane];
#pragma unroll
        for (int h = 0; h < H; h++) acc[h] += av[h] * hv;
    }
#pragma unroll
    for (int h = 0; h < H; h++)
        agg[(size_t)n * (H * DH) + h * DH + lane] = (half_t)acc[h];
}

// ---------------- out via MFMA: D[16n x 64j] = agg[16n x C] * Wt^T[C x 64] ----------------

template <int H>
__global__ void k_out_mfma(const half_t* __restrict__ agg, const half_t* __restrict__ wt,
                           const float* __restrict__ bias, const float* __restrict__ hin,
                           float* __restrict__ hout, half_t* __restrict__ h16out) {
    constexpr int C = H * DH;
    constexpr int KS = C / 32;
    int gid = blockIdx.x * blockDim.x + threadIdx.x;
    int wave = gid >> 6;
    int lane = gid & 63;
    if (wave >= NN / 16) return;
    int n0 = wave * 16;
    int r  = lane & 15;
    int kb = lane >> 4;

    f16x8 afrag[KS];
#pragma unroll
    for (int s = 0; s < KS; s++)
        afrag[s] = *(const f16x8*)(agg + (size_t)(n0 + r) * C + s * 32 + kb * 8);

#pragma unroll
    for (int ct = 0; ct < 4; ct++) {
        f32x4 acc = {0.f, 0.f, 0.f, 0.f};
#pragma unroll
        for (int s = 0; s < KS; s++) {
            f16x8 bfrag = *(const f16x8*)(wt + (size_t)(ct * 16 + r) * C + s * 32 + kb * 8);
            acc = __builtin_amdgcn_mfma_f32_16x16x32_f16(afrag[s], bfrag, acc, 0, 0, 0);
        }
        int j = ct * 16 + r;
        float bj = bias[j];
#pragma unroll
        for (int i = 0; i < 4; i++) {
            int n = n0 + kb * 4 + i;
            float v = acc[i] * (1.0f / H) + bj;
            v = fmaxf(v, 0.f) + hin[(size_t)n * DH + j];
            hout[(size_t)n * DH + j] = v;
            h16out[(size_t)n * DH + j] = (half_t)v;
        }
    }
}

// ---------------- final MLP head ----------------

__global__ void k_head_s(const float* __restrict__ h, const float* __restrict__ fc1_W,
                         const float* __restrict__ fc1_b, const float* __restrict__ fc2_W,
                         const float* __restrict__ fc2_b, float* __restrict__ out) {
    int n = blockIdx.x * blockDim.x + threadIdx.x;
    if (n >= NN) return;
    float y[32];
#pragma unroll
    for (int c = 0; c < 32; c++) y[c] = fc1_b[c];
    for (int k = 0; k < DH; k++) {
        float hk = h[n * DH + k];
#pragma unroll
        for (int c = 0; c < 32; c++) y[c] += hk * fc1_W[k * 32 + c];
    }
    float o0 = fc2_b[0], o1 = fc2_b[1];
#pragma unroll
    for (int c = 0; c < 32; c++) {
        float yr = fmaxf(y[c], 0.f);
        o0 += yr * fc2_W[c * 2];
        o1 += yr * fc2_W[c * 2 + 1];
    }
    out[2 * n] = tanhf(o0);
    out[2 * n + 1] = tanhf(o1);
}

// ---------------- launch ----------------

extern "C" void kernel_launch(void* const* d_in, const int* in_sizes, int n_in,
                              void* d_out, int out_size, void* d_ws, size_t ws_size,
                              hipStream_t stream) {
    const float* x     = (const float*)d_in[0];
    const int*   ei    = (const int*)d_in[1];
    const float* ea    = (const float*)d_in[2];
    const float* enc_W = (const float*)d_in[3];
    const float* enc_b = (const float*)d_in[4];
    const float* lin_W[3]    = {(const float*)d_in[5],  (const float*)d_in[11], (const float*)d_in[17]};
    const float* att_src[3]  = {(const float*)d_in[6],  (const float*)d_in[12], (const float*)d_in[18]};
    const float* att_dst[3]  = {(const float*)d_in[7],  (const float*)d_in[13], (const float*)d_in[19]};
    const float* edge_W[3]   = {(const float*)d_in[8],  (const float*)d_in[14], (const float*)d_in[20]};
    const float* att_edge[3] = {(const float*)d_in[9],  (const float*)d_in[15], (const float*)d_in[21]};
    const float* bias[3]     = {(const float*)d_in[10], (const float*)d_in[16], (const float*)d_in[22]};
    const float* fc1_W = (const float*)d_in[23];
    const float* fc1_b = (const float*)d_in[24];
    const float* fc2_W = (const float*)d_in[25];
    const float* fc2_b = (const float*)d_in[26];
    float* out = (float*)d_out;

    char* p = (char*)d_ws;
    auto alloc = [&](size_t bytes) -> void* {
        void* r = (void*)p;
        p += (bytes + 255) & ~(size_t)255;
        return r;
    };
    int*    deg    = (int*)alloc((size_t)NN * 4);
    int*    part   = (int*)alloc((size_t)NCHUNK * 4);
    int*    row    = (int*)alloc((size_t)(NN + 1) * 4);
    int*    cursor = (int*)alloc((size_t)NN * 4);
    int2*   csr    = (int2*)alloc((size_t)ETOT * 8);
    float*  a_srcB = (float*)alloc((size_t)NN * 4 * 4);
    float*  a_dstB = (float*)alloc((size_t)NN * 4 * 4);
    float*  wsrcA  = (float*)alloc(576 * 4);
    float*  wdstA  = (float*)alloc(576 * 4);
    float*  coefA  = (float*)alloc(18 * 4);
    half_t* wtA    = (half_t*)alloc((size_t)(16384 * 2 + 4096) * 2);
    half_t* abuf   = (half_t*)alloc((size_t)ETOT * 4 * 2);
    half_t* aggB   = (half_t*)alloc((size_t)NN * 256 * 2);
    half_t* h16    = (half_t*)alloc((size_t)NN * DH * 2);
    float*  hA     = (float*)alloc((size_t)NN * DH * 4);
    float*  hB     = (float*)alloc((size_t)NN * DH * 4);

    const int BT = 256;
    const int nodeBlocks  = (NN + BT - 1) / BT;
    const int edgeBlocks  = (NE + BT - 1) / BT;
    const int chunkBlocks = (NCHUNK + BT - 1) / BT;
    const int ndBlocks    = (NN * DH + BT - 1) / BT;
    const int nodeWaveBlocks = (NN * 64 + BT - 1) / BT;
    const int mfmaBlocks  = ((NN / 16) * 64 + BT - 1) / BT;

    k_zero_init<<<nodeBlocks, BT, 0, stream>>>(deg);
    k_deg<<<edgeBlocks, BT, 0, stream>>>(ei, deg);
    k_scan_a<<<chunkBlocks, BT, 0, stream>>>(deg, part);
    k_scan_b<<<1, 64, 0, stream>>>(part);
    k_scan_c<<<chunkBlocks, BT, 0, stream>>>(deg, part, row, cursor);
    k_fill_csr<<<edgeBlocks, BT, 0, stream>>>(ei, ea, cursor, csr);
    k_fill_self<<<nodeBlocks, BT, 0, stream>>>(deg, row, csr);
    k_encoder<<<ndBlocks, BT, 0, stream>>>(x, enc_W, enc_b, hA, h16);
    k_prep<<<3, 64, 0, stream>>>(lin_W[0], att_src[0], att_dst[0], edge_W[0], att_edge[0],
                                 lin_W[1], att_src[1], att_dst[1], edge_W[1], att_edge[1],
                                 lin_W[2], att_src[2], att_dst[2], edge_W[2], att_edge[2],
                                 wsrcA, wdstA, coefA, wtA);

    float* hin = hA;
    float* hout = hB;

    for (int L = 0; L < 3; L++) {
        const float* ws = wsrcA + ((L == 0) ? 0 : (L == 1) ? 256 : 512);
        const float* wd = wdstA + ((L == 0) ? 0 : (L == 1) ? 256 : 512);
        const float* cf = coefA + ((L == 0) ? 0 : (L == 1) ? 8 : 16);
        const half_t* wt = wtA + ((L == 0) ? 0 : (L == 1) ? 16384 : 32768);
        if (L < 2) {
            constexpr int H = 4;
            k_att_h<H><<<nodeBlocks, BT, 0, stream>>>(hin, ws, wd, a_srcB, a_dstB);
            k_mden<H><<<nodeBlocks, BT, 0, stream>>>(row, csr, a_srcB, a_dstB, cf, abuf);
            k_agg_h<H><<<nodeWaveBlocks, BT, 0, stream>>>(row, csr, abuf, h16, aggB);
            k_out_mfma<H><<<mfmaBlocks, BT, 0, stream>>>(aggB, wt, bias[L], hin, hout, h16);
        } else {
            constexpr int H = 1;
            k_att_h<H><<<nodeBlocks, BT, 0, stream>>>(hin, ws, wd, a_srcB, a_dstB);
            k_mden<H><<<nodeBlocks, BT, 0, stream>>>(row, csr, a_srcB, a_dstB, cf, abuf);
            k_agg_h<H><<<nodeWaveBlocks, BT, 0, stream>>>(row, csr, abuf, h16, aggB);
            k_out_mfma<H><<<mfmaBlocks, BT, 0, stream>>>(aggB, wt, bias[L], hin, hout, h16);
        }
        float* t = hin; hin = hout; hout = t;
    }
    k_head_s<<<nodeBlocks, BT, 0, stream>>>(hin, fc1_W, fc1_b, fc2_W, fc2_b, out);
}

// Round 16
// 598.797 us; speedup vs baseline: 1.3677x; 1.0513x over previous
//
#include <hip/hip_runtime.h>
#include <math.h>

#define NN 100000
#define NE 1000000
#define DH 64
constexpr int ETOT = NE + NN;
constexpr int CHUNK = 100;
constexpr int NCHUNK = (NN + CHUNK - 1) / CHUNK;   // 1000

typedef _Float16 half_t;
typedef _Float16 f16x8 __attribute__((ext_vector_type(8)));
typedef float f32x4 __attribute__((ext_vector_type(4)));

// AoS edge record (8B): {int src; half2 ea} stored as int2

union h2u {
    int i;
    struct { unsigned short lo, hi; } u;
};
__device__ inline int pack_ea(float a, float b) {
    half_t ha = (half_t)a, hb = (half_t)b;
    h2u v;
    v.u.lo = *(unsigned short*)&ha;
    v.u.hi = *(unsigned short*)&hb;
    return v.i;
}
__device__ inline void unpack_ea(int p, float& a, float& b) {
    h2u v; v.i = p;
    half_t ha = *(half_t*)&v.u.lo;
    half_t hb = *(half_t*)&v.u.hi;
    a = (float)ha; b = (float)hb;
}

// ---------------- degree ----------------

__global__ void k_zero_init(int* __restrict__ deg) {
    int i = blockIdx.x * blockDim.x + threadIdx.x;
    if (i < NN) deg[i] = 0;
}

__global__ void k_deg(const int* __restrict__ ei, int* __restrict__ deg) {
    int e = blockIdx.x * blockDim.x + threadIdx.x;
    if (e < NE) atomicAdd(&deg[ei[NE + e]], 1);
}

// ---------------- chunked prefix scan (scalar) ----------------

__global__ void k_scan_a(const int* __restrict__ deg, int* __restrict__ part) {
    int c = blockIdx.x * blockDim.x + threadIdx.x;
    if (c >= NCHUNK) return;
    int lo = c * CHUNK;
    int hi = lo + CHUNK; if (hi > NN) hi = NN;
    int s = 0;
    for (int i = lo; i < hi; i++) s += deg[i];
    part[c] = s;
}

__global__ void k_scan_b(int* __restrict__ part) {
    if (threadIdx.x || blockIdx.x) return;
    int run = 0;
    for (int i = 0; i < NCHUNK; i++) { int t = part[i]; part[i] = run; run += t; }
}

__global__ void k_scan_c(const int* __restrict__ deg, const int* __restrict__ part,
                         int* __restrict__ row, int* __restrict__ cursor) {
    int c = blockIdx.x * blockDim.x + threadIdx.x;
    if (c >= NCHUNK) return;
    int lo = c * CHUNK;
    int hi = lo + CHUNK; if (hi > NN) hi = NN;
    int run = part[c];
    for (int i = lo; i < hi; i++) {
        int r = run + i;
        row[i] = r;
        cursor[i] = r;
        run += deg[i];
    }
    if (c == NCHUNK - 1) row[NN] = run + NN;
}

__global__ void k_fill_csr(const int* __restrict__ ei, const float* __restrict__ ea,
                           int* __restrict__ cursor, int2* __restrict__ csr) {
    int e = blockIdx.x * blockDim.x + threadIdx.x;
    if (e < NE) {
        int s = ei[e];
        int d = ei[NE + e];
        int pos = atomicAdd(&cursor[d], 1);
        int2 rec;
        rec.x = s;
        rec.y = pack_ea(ea[2 * e], ea[2 * e + 1]);
        csr[pos] = rec;
    }
}

__global__ void k_fill_self(const int* __restrict__ deg, const int* __restrict__ row,
                            int2* __restrict__ csr) {
    int n = blockIdx.x * blockDim.x + threadIdx.x;
    if (n >= NN) return;
    int r0 = row[n];
    int dg = deg[n];
    float s0 = 0.f, s1 = 0.f;
    for (int j = r0; j < r0 + dg; j++) {
        float e0, e1;
        unpack_ea(csr[j].y, e0, e1);
        s0 += e0; s1 += e1;
    }
    float dv = fmaxf((float)dg, 1.0f);
    int2 self;
    self.x = n;
    self.y = pack_ea(s0 / dv, s1 / dv);
    csr[r0 + dg] = self;
}

// ---------------- encoder: h16 = relu(x @ enc_W + enc_b) ----------------

__global__ void k_encoder(const float* __restrict__ x, const float* __restrict__ W,
                          const float* __restrict__ b, half_t* __restrict__ h16) {
    int idx = blockIdx.x * blockDim.x + threadIdx.x;
    int n = idx >> 6, d = idx & 63;
    if (n < NN) {
        float v = x[2 * n] * W[d] + x[2 * n + 1] * W[DH + d] + b[d];
        h16[idx] = (half_t)fmaxf(v, 0.f);
    }
}

// ---------------- fused prep (all 3 layers): wsrc/wdst, coef, MFMA B-operand Wt ------------

__global__ void k_prep(const float* __restrict__ lw0, const float* __restrict__ as0,
                       const float* __restrict__ ad0, const float* __restrict__ ew0,
                       const float* __restrict__ ae0,
                       const float* __restrict__ lw1, const float* __restrict__ as1,
                       const float* __restrict__ ad1, const float* __restrict__ ew1,
                       const float* __restrict__ ae1,
                       const float* __restrict__ lw2, const float* __restrict__ as2,
                       const float* __restrict__ ad2, const float* __restrict__ ew2,
                       const float* __restrict__ ae2,
                       float* __restrict__ wsrc, float* __restrict__ wdst,
                       float* __restrict__ coef, half_t* __restrict__ wt) {
    int L = blockIdx.x;
    int k = threadIdx.x;
    if (k >= DH) return;
    const float* lw = (L == 0) ? lw0 : (L == 1) ? lw1 : lw2;
    const float* as = (L == 0) ? as0 : (L == 1) ? as1 : as2;
    const float* ad = (L == 0) ? ad0 : (L == 1) ? ad1 : ad2;
    const float* ew = (L == 0) ? ew0 : (L == 1) ? ew1 : ew2;
    const float* ae = (L == 0) ? ae0 : (L == 1) ? ae1 : ae2;
    int H = (L < 2) ? 4 : 1;
    int C = H * DH;
    int wo = (L == 0) ? 0 : (L == 1) ? 256 : 512;
    int wto = (L == 0) ? 0 : (L == 1) ? 16384 : 32768;
    for (int h = 0; h < H; h++) {
        float ss = 0.f, sd = 0.f;
        for (int d = 0; d < DH; d++) {
            float w = lw[(size_t)k * C + h * DH + d];
            ss += w * as[h * DH + d];
            sd += w * ad[h * DH + d];
        }
        wsrc[wo + k * H + h] = ss;
        wdst[wo + k * H + h] = sd;
    }
    for (int c = 0; c < C; c++)
        wt[wto + k * C + c] = (half_t)lw[(size_t)(c & 63) * C + (c >> 6) * 64 + k];
    if (k == 0) {
        int co = (L == 0) ? 0 : (L == 1) ? 8 : 16;
        for (int w = 0; w < 2; w++)
            for (int h = 0; h < H; h++) {
                float s = 0.f;
                for (int d = 0; d < DH; d++)
                    s += ew[w * H * DH + h * DH + d] * ae[h * DH + d];
                coef[co + w * H + h] = s;
            }
    }
}

// ---------------- a_src/a_dst from h16: one thread per node ----------------

template <int H>
__global__ void k_att_h(const half_t* __restrict__ h, const float* __restrict__ wsrc,
                        const float* __restrict__ wdst,
                        float* __restrict__ a_src, float* __restrict__ a_dst) {
    int n = blockIdx.x * blockDim.x + threadIdx.x;
    if (n >= NN) return;
    float as[H], ad[H];
#pragma unroll
    for (int hh = 0; hh < H; hh++) { as[hh] = 0.f; ad[hh] = 0.f; }
    const half_t* hr = h + (size_t)n * DH;
    for (int q = 0; q < DH / 8; q++) {
        float4 raw = *(const float4*)(hr + q * 8);
        const half_t* hp = (const half_t*)&raw;
#pragma unroll
        for (int t = 0; t < 8; t++) {
            float hv = (float)hp[t];
            int k = q * 8 + t;
#pragma unroll
            for (int hh = 0; hh < H; hh++) {
                as[hh] += hv * wsrc[k * H + hh];
                ad[hh] += hv * wdst[k * H + hh];
            }
        }
    }
#pragma unroll
    for (int hh = 0; hh < H; hh++) {
        a_src[n * H + hh] = as[hh];
        a_dst[n * H + hh] = ad[hh];
    }
}

// ---------------- per-node den + alpha (fp16): SINGLE CSR pass + linear rescale ----------------
// ex_s = exp(lg)*2^-5 (scale cancels in alpha = ex_s/sum(ex_s); e^10/32=690 << fp16 max)

template <int H>
__global__ void k_mden(const int* __restrict__ row, const int2* __restrict__ csr,
                       const float* __restrict__ a_src, const float* __restrict__ a_dst,
                       const float* __restrict__ coef, half_t* __restrict__ abuf) {
    int n = blockIdx.x * blockDim.x + threadIdx.x;
    if (n >= NN) return;
    int r0 = row[n], r1 = row[n + 1];
    float ad[H], cf[2 * H], den[H];
#pragma unroll
    for (int h = 0; h < H; h++) { ad[h] = a_dst[n * H + h]; den[h] = 0.f; }
#pragma unroll
    for (int i = 0; i < 2 * H; i++) cf[i] = coef[i];
    for (int j = r0; j < r1; j++) {
        int2 rec = csr[j];
        int s = rec.x;
        float e0, e1;
        unpack_ea(rec.y, e0, e1);
        half_t a4[H];
#pragma unroll
        for (int h = 0; h < H; h++) {
            float lg = a_src[s * H + h] + ad[h] + e0 * cf[h] + e1 * cf[H + h];
            lg = (lg > 0.f) ? lg : 0.2f * lg;
            half_t ex = (half_t)(__expf(lg) * 0.03125f);
            den[h] += (float)ex;                    // sum the ROUNDED values
            a4[h] = ex;
        }
        if constexpr (H == 4) {
            *(float2*)(abuf + (size_t)j * 4) = *(float2*)a4;
        } else {
            abuf[j] = a4[0];
        }
    }
    float inv[H];
#pragma unroll
    for (int h = 0; h < H; h++) inv[h] = 1.f / (den[h] + 1e-16f);
    // linear rescale pass (abuf hot in cache; no csr read, no gathers, no exp)
    for (int j = r0; j < r1; j++) {
        if constexpr (H == 4) {
            float2 raw = *(float2*)(abuf + (size_t)j * 4);
            half_t* ap = (half_t*)&raw;
            half_t a4[4];
#pragma unroll
            for (int h = 0; h < 4; h++) a4[h] = (half_t)((float)ap[h] * inv[h]);
            *(float2*)(abuf + (size_t)j * 4) = *(float2*)a4;
        } else {
            abuf[j] = (half_t)((float)abuf[j] * inv[0]);
        }
    }
}

// ---------------- aggregate on h: one WAVE per node, lane = k, 4-edge pipelined ----------------

template <int H>
__global__ void k_agg_h(const int* __restrict__ row, const int2* __restrict__ csr,
                        const half_t* __restrict__ abuf, const half_t* __restrict__ h16,
                        half_t* __restrict__ agg) {
    int gid = blockIdx.x * blockDim.x + threadIdx.x;
    int n = gid >> 6;
    int lane = gid & 63;
    if (n >= NN) return;
    int r0 = row[n], r1 = row[n + 1];
    float acc[H];
#pragma unroll
    for (int h = 0; h < H; h++) acc[h] = 0.f;
    int j = r0;
    for (; j + 4 <= r1; j += 4) {
        int s0 = csr[j].x, s1 = csr[j + 1].x, s2 = csr[j + 2].x, s3 = csr[j + 3].x;
        float av[4][H];
        if constexpr (H == 4) {
            float2 r0v = *(const float2*)(abuf + (size_t)(j + 0) * 4);
            float2 r1v = *(const float2*)(abuf + (size_t)(j + 1) * 4);
            float2 r2v = *(const float2*)(abuf + (size_t)(j + 2) * 4);
            float2 r3v = *(const float2*)(abuf + (size_t)(j + 3) * 4);
            const half_t* p0 = (const half_t*)&r0v;
            const half_t* p1 = (const half_t*)&r1v;
            const half_t* p2 = (const half_t*)&r2v;
            const half_t* p3 = (const half_t*)&r3v;
#pragma unroll
            for (int h = 0; h < 4; h++) {
                av[0][h] = (float)p0[h]; av[1][h] = (float)p1[h];
                av[2][h] = (float)p2[h]; av[3][h] = (float)p3[h];
            }
        } else {
            av[0][0] = (float)abuf[j];     av[1][0] = (float)abuf[j + 1];
            av[2][0] = (float)abuf[j + 2]; av[3][0] = (float)abuf[j + 3];
        }
        float hv0 = (float)h16[(size_t)s0 * DH + lane];
        float hv1 = (float)h16[(size_t)s1 * DH + lane];
        float hv2 = (float)h16[(size_t)s2 * DH + lane];
        float hv3 = (float)h16[(size_t)s3 * DH + lane];
#pragma unroll
        for (int h = 0; h < H; h++) acc[h] += av[0][h] * hv0;
#pragma unroll
        for (int h = 0; h < H; h++) acc[h] += av[1][h] * hv1;
#pragma unroll
        for (int h = 0; h < H; h++) acc[h] += av[2][h] * hv2;
#pragma unroll
        for (int h = 0; h < H; h++) acc[h] += av[3][h] * hv3;
    }
    for (; j < r1; j++) {
        int s = csr[j].x;
        float av[H];
        if constexpr (H == 4) {
            float2 raw = *(const float2*)(abuf + (size_t)j * 4);
            const half_t* ap = (const half_t*)&raw;
#pragma unroll
            for (int h = 0; h < H; h++) av[h] = (float)ap[h];
        } else {
            av[0] = (float)abuf[j];
        }
        float hv = (float)h16[(size_t)s * DH + lane];
#pragma unroll
        for (int h = 0; h < H; h++) acc[h] += av[h] * hv;
    }
#pragma unroll
    for (int h = 0; h < H; h++)
        agg[(size_t)n * (H * DH) + h * DH + lane] = (half_t)acc[h];
}

// ---------------- out via MFMA: fp16-only residual chain ----------------

template <int H>
__global__ void k_out_mfma(const half_t* __restrict__ agg, const half_t* __restrict__ wt,
                           const float* __restrict__ bias, const half_t* __restrict__ h16in,
                           half_t* __restrict__ h16out) {
    constexpr int C = H * DH;
    constexpr int KS = C / 32;
    int gid = blockIdx.x * blockDim.x + threadIdx.x;
    int wave = gid >> 6;
    int lane = gid & 63;
    if (wave >= NN / 16) return;
    int n0 = wave * 16;
    int r  = lane & 15;
    int kb = lane >> 4;

    f16x8 afrag[KS];
#pragma unroll
    for (int s = 0; s < KS; s++)
        afrag[s] = *(const f16x8*)(agg + (size_t)(n0 + r) * C + s * 32 + kb * 8);

#pragma unroll
    for (int ct = 0; ct < 4; ct++) {
        f32x4 acc = {0.f, 0.f, 0.f, 0.f};
#pragma unroll
        for (int s = 0; s < KS; s++) {
            f16x8 bfrag = *(const f16x8*)(wt + (size_t)(ct * 16 + r) * C + s * 32 + kb * 8);
            acc = __builtin_amdgcn_mfma_f32_16x16x32_f16(afrag[s], bfrag, acc, 0, 0, 0);
        }
        int j = ct * 16 + r;
        float bj = bias[j];
#pragma unroll
        for (int i = 0; i < 4; i++) {
            int n = n0 + kb * 4 + i;
            float v = acc[i] * (1.0f / H) + bj;
            v = fmaxf(v, 0.f) + (float)h16in[(size_t)n * DH + j];
            h16out[(size_t)n * DH + j] = (half_t)v;
        }
    }
}

// ---------------- final MLP head (reads fp16 h) ----------------

__global__ void k_head_s(const half_t* __restrict__ h, const float* __restrict__ fc1_W,
                         const float* __restrict__ fc1_b, const float* __restrict__ fc2_W,
                         const float* __restrict__ fc2_b, float* __restrict__ out) {
    int n = blockIdx.x * blockDim.x + threadIdx.x;
    if (n >= NN) return;
    float y[32];
#pragma unroll
    for (int c = 0; c < 32; c++) y[c] = fc1_b[c];
    const half_t* hr = h + (size_t)n * DH;
    for (int q = 0; q < DH / 8; q++) {
        float4 raw = *(const float4*)(hr + q * 8);
        const half_t* hp = (const half_t*)&raw;
#pragma unroll
        for (int t = 0; t < 8; t++) {
            float hk = (float)hp[t];
            int k = q * 8 + t;
#pragma unroll
            for (int c = 0; c < 32; c++) y[c] += hk * fc1_W[k * 32 + c];
        }
    }
    float o0 = fc2_b[0], o1 = fc2_b[1];
#pragma unroll
    for (int c = 0; c < 32; c++) {
        float yr = fmaxf(y[c], 0.f);
        o0 += yr * fc2_W[c * 2];
        o1 += yr * fc2_W[c * 2 + 1];
    }
    out[2 * n] = tanhf(o0);
    out[2 * n + 1] = tanhf(o1);
}

// ---------------- launch ----------------

extern "C" void kernel_launch(void* const* d_in, const int* in_sizes, int n_in,
                              void* d_out, int out_size, void* d_ws, size_t ws_size,
                              hipStream_t stream) {
    const float* x     = (const float*)d_in[0];
    const int*   ei    = (const int*)d_in[1];
    const float* ea    = (const float*)d_in[2];
    const float* enc_W = (const float*)d_in[3];
    const float* enc_b = (const float*)d_in[4];
    const float* lin_W[3]    = {(const float*)d_in[5],  (const float*)d_in[11], (const float*)d_in[17]};
    const float* att_src[3]  = {(const float*)d_in[6],  (const float*)d_in[12], (const float*)d_in[18]};
    const float* att_dst[3]  = {(const float*)d_in[7],  (const float*)d_in[13], (const float*)d_in[19]};
    const float* edge_W[3]   = {(const float*)d_in[8],  (const float*)d_in[14], (const float*)d_in[20]};
    const float* att_edge[3] = {(const float*)d_in[9],  (const float*)d_in[15], (const float*)d_in[21]};
    const float* bias[3]     = {(const float*)d_in[10], (const float*)d_in[16], (const float*)d_in[22]};
    const float* fc1_W = (const float*)d_in[23];
    const float* fc1_b = (const float*)d_in[24];
    const float* fc2_W = (const float*)d_in[25];
    const float* fc2_b = (const float*)d_in[26];
    float* out = (float*)d_out;

    char* p = (char*)d_ws;
    auto alloc = [&](size_t bytes) -> void* {
        void* r = (void*)p;
        p += (bytes + 255) & ~(size_t)255;
        return r;
    };
    int*    deg    = (int*)alloc((size_t)NN * 4);
    int*    part   = (int*)alloc((size_t)NCHUNK * 4);
    int*    row    = (int*)alloc((size_t)(NN + 1) * 4);
    int*    cursor = (int*)alloc((size_t)NN * 4);
    int2*   csr    = (int2*)alloc((size_t)ETOT * 8);
    float*  a_srcB = (float*)alloc((size_t)NN * 4 * 4);
    float*  a_dstB = (float*)alloc((size_t)NN * 4 * 4);
    float*  wsrcA  = (float*)alloc(576 * 4);
    float*  wdstA  = (float*)alloc(576 * 4);
    float*  coefA  = (float*)alloc(18 * 4);
    half_t* wtA    = (half_t*)alloc((size_t)(16384 * 2 + 4096) * 2);
    half_t* abuf   = (half_t*)alloc((size_t)ETOT * 4 * 2);
    half_t* aggB   = (half_t*)alloc((size_t)NN * 256 * 2);
    half_t* h16A   = (half_t*)alloc((size_t)NN * DH * 2);
    half_t* h16B   = (half_t*)alloc((size_t)NN * DH * 2);

    const int BT = 256;
    const int nodeBlocks  = (NN + BT - 1) / BT;
    const int edgeBlocks  = (NE + BT - 1) / BT;
    const int chunkBlocks = (NCHUNK + BT - 1) / BT;
    const int ndBlocks    = (NN * DH + BT - 1) / BT;
    const int nodeWaveBlocks = (NN * 64 + BT - 1) / BT;
    const int mfmaBlocks  = ((NN / 16) * 64 + BT - 1) / BT;

    k_zero_init<<<nodeBlocks, BT, 0, stream>>>(deg);
    k_deg<<<edgeBlocks, BT, 0, stream>>>(ei, deg);
    k_scan_a<<<chunkBlocks, BT, 0, stream>>>(deg, part);
    k_scan_b<<<1, 64, 0, stream>>>(part);
    k_scan_c<<<chunkBlocks, BT, 0, stream>>>(deg, part, row, cursor);
    k_fill_csr<<<edgeBlocks, BT, 0, stream>>>(ei, ea, cursor, csr);
    k_fill_self<<<nodeBlocks, BT, 0, stream>>>(deg, row, csr);
    k_encoder<<<ndBlocks, BT, 0, stream>>>(x, enc_W, enc_b, h16A);
    k_prep<<<3, 64, 0, stream>>>(lin_W[0], att_src[0], att_dst[0], edge_W[0], att_edge[0],
                                 lin_W[1], att_src[1], att_dst[1], edge_W[1], att_edge[1],
                                 lin_W[2], att_src[2], att_dst[2], edge_W[2], att_edge[2],
                                 wsrcA, wdstA, coefA, wtA);

    half_t* hin = h16A;
    half_t* hout = h16B;

    for (int L = 0; L < 3; L++) {
        const float* ws = wsrcA + ((L == 0) ? 0 : (L == 1) ? 256 : 512);
        const float* wd = wdstA + ((L == 0) ? 0 : (L == 1) ? 256 : 512);
        const float* cf = coefA + ((L == 0) ? 0 : (L == 1) ? 8 : 16);
        const half_t* wt = wtA + ((L == 0) ? 0 : (L == 1) ? 16384 : 32768);
        if (L < 2) {
            constexpr int H = 4;
            k_att_h<H><<<nodeBlocks, BT, 0, stream>>>(hin, ws, wd, a_srcB, a_dstB);
            k_mden<H><<<nodeBlocks, BT, 0, stream>>>(row, csr, a_srcB, a_dstB, cf, abuf);
            k_agg_h<H><<<nodeWaveBlocks, BT, 0, stream>>>(row, csr, abuf, hin, aggB);
            k_out_mfma<H><<<mfmaBlocks, BT, 0, stream>>>(aggB, wt, bias[L], hin, hout);
        } else {
            constexpr int H = 1;
            k_att_h<H><<<nodeBlocks, BT, 0, stream>>>(hin, ws, wd, a_srcB, a_dstB);
            k_mden<H><<<nodeBlocks, BT, 0, stream>>>(row, csr, a_srcB, a_dstB, cf, abuf);
            k_agg_h<H><<<nodeWaveBlocks, BT, 0, stream>>>(row, csr, abuf, hin, aggB);
            k_out_mfma<H><<<mfmaBlocks, BT, 0, stream>>>(aggB, wt, bias[L], hin, hout);
        }
        half_t* t = hin; hin = hout; hout = t;
    }
    k_head_s<<<nodeBlocks, BT, 0, stream>>>(hin, fc1_W, fc1_b, fc2_W, fc2_b, out);
}

// Round 17
// 546.207 us; speedup vs baseline: 1.4994x; 1.0963x over previous
//
#include <hip/hip_runtime.h>
#include <math.h>

#define NN 100000
#define NE 1000000
#define DH 64
constexpr int ETOT = NE + NN;
constexpr int CHUNK = 100;
constexpr int NCHUNK = (NN + CHUNK - 1) / CHUNK;   // 1000

typedef _Float16 half_t;
typedef _Float16 f16x8 __attribute__((ext_vector_type(8)));
typedef float f32x4 __attribute__((ext_vector_type(4)));

// AoS edge record (8B): {int src; half2 ea} stored as int2

union h2u {
    int i;
    struct { unsigned short lo, hi; } u;
};
__device__ inline int pack_ea(float a, float b) {
    half_t ha = (half_t)a, hb = (half_t)b;
    h2u v;
    v.u.lo = *(unsigned short*)&ha;
    v.u.hi = *(unsigned short*)&hb;
    return v.i;
}
__device__ inline void unpack_ea(int p, float& a, float& b) {
    h2u v; v.i = p;
    half_t ha = *(half_t*)&v.u.lo;
    half_t hb = *(half_t*)&v.u.hi;
    a = (float)ha; b = (float)hb;
}

// ---------------- degree + per-edge rank (atomic returns rank within dst segment) ------------

__global__ void k_zero_init(int* __restrict__ deg) {
    int i = blockIdx.x * blockDim.x + threadIdx.x;
    if (i < NN) deg[i] = 0;
}

__global__ void k_deg(const int* __restrict__ ei, int* __restrict__ deg, int* __restrict__ rank) {
    int e = blockIdx.x * blockDim.x + threadIdx.x;
    if (e < NE) rank[e] = atomicAdd(&deg[ei[NE + e]], 1);
}

// ---------------- chunked prefix scan (scalar) ----------------

__global__ void k_scan_a(const int* __restrict__ deg, int* __restrict__ part) {
    int c = blockIdx.x * blockDim.x + threadIdx.x;
    if (c >= NCHUNK) return;
    int lo = c * CHUNK;
    int hi = lo + CHUNK; if (hi > NN) hi = NN;
    int s = 0;
    for (int i = lo; i < hi; i++) s += deg[i];
    part[c] = s;
}

__global__ void k_scan_b(int* __restrict__ part) {
    if (threadIdx.x || blockIdx.x) return;
    int run = 0;
    for (int i = 0; i < NCHUNK; i++) { int t = part[i]; part[i] = run; run += t; }
}

__global__ void k_scan_c(const int* __restrict__ deg, const int* __restrict__ part,
                         int* __restrict__ row) {
    int c = blockIdx.x * blockDim.x + threadIdx.x;
    if (c >= NCHUNK) return;
    int lo = c * CHUNK;
    int hi = lo + CHUNK; if (hi > NN) hi = NN;
    int run = part[c];
    for (int i = lo; i < hi; i++) {
        row[i] = run + i;
        run += deg[i];
    }
    if (c == NCHUNK - 1) row[NN] = run + NN;
}

// pure scatter, no atomics: position = row[d] + rank[e]
__global__ void k_fill_csr(const int* __restrict__ ei, const float* __restrict__ ea,
                           const int* __restrict__ row, const int* __restrict__ rank,
                           int2* __restrict__ csr) {
    int e = blockIdx.x * blockDim.x + threadIdx.x;
    if (e < NE) {
        int s = ei[e];
        int d = ei[NE + e];
        int pos = row[d] + rank[e];
        int2 rec;
        rec.x = s;
        rec.y = pack_ea(ea[2 * e], ea[2 * e + 1]);
        csr[pos] = rec;
    }
}

__global__ void k_fill_self(const int* __restrict__ deg, const int* __restrict__ row,
                            int2* __restrict__ csr) {
    int n = blockIdx.x * blockDim.x + threadIdx.x;
    if (n >= NN) return;
    int r0 = row[n];
    int dg = deg[n];
    float s0 = 0.f, s1 = 0.f;
    for (int j = r0; j < r0 + dg; j++) {
        float e0, e1;
        unpack_ea(csr[j].y, e0, e1);
        s0 += e0; s1 += e1;
    }
    float dv = fmaxf((float)dg, 1.0f);
    int2 self;
    self.x = n;
    self.y = pack_ea(s0 / dv, s1 / dv);
    csr[r0 + dg] = self;
}

// ---------------- encoder: h16 = relu(x @ enc_W + enc_b) ----------------

__global__ void k_encoder(const float* __restrict__ x, const float* __restrict__ W,
                          const float* __restrict__ b, half_t* __restrict__ h16) {
    int idx = blockIdx.x * blockDim.x + threadIdx.x;
    int n = idx >> 6, d = idx & 63;
    if (n < NN) {
        float v = x[2 * n] * W[d] + x[2 * n + 1] * W[DH + d] + b[d];
        h16[idx] = (half_t)fmaxf(v, 0.f);
    }
}

// ---------------- fused prep (all 3 layers): wsrc/wdst, coef, MFMA B-operand Wt ------------

__global__ void k_prep(const float* __restrict__ lw0, const float* __restrict__ as0,
                       const float* __restrict__ ad0, const float* __restrict__ ew0,
                       const float* __restrict__ ae0,
                       const float* __restrict__ lw1, const float* __restrict__ as1,
                       const float* __restrict__ ad1, const float* __restrict__ ew1,
                       const float* __restrict__ ae1,
                       const float* __restrict__ lw2, const float* __restrict__ as2,
                       const float* __restrict__ ad2, const float* __restrict__ ew2,
                       const float* __restrict__ ae2,
                       float* __restrict__ wsrc, float* __restrict__ wdst,
                       float* __restrict__ coef, half_t* __restrict__ wt) {
    int L = blockIdx.x;
    int k = threadIdx.x;
    if (k >= DH) return;
    const float* lw = (L == 0) ? lw0 : (L == 1) ? lw1 : lw2;
    const float* as = (L == 0) ? as0 : (L == 1) ? as1 : as2;
    const float* ad = (L == 0) ? ad0 : (L == 1) ? ad1 : ad2;
    const float* ew = (L == 0) ? ew0 : (L == 1) ? ew1 : ew2;
    const float* ae = (L == 0) ? ae0 : (L == 1) ? ae1 : ae2;
    int H = (L < 2) ? 4 : 1;
    int C = H * DH;
    int wo = (L == 0) ? 0 : (L == 1) ? 256 : 512;
    int wto = (L == 0) ? 0 : (L == 1) ? 16384 : 32768;
    for (int h = 0; h < H; h++) {
        float ss = 0.f, sd = 0.f;
        for (int d = 0; d < DH; d++) {
            float w = lw[(size_t)k * C + h * DH + d];
            ss += w * as[h * DH + d];
            sd += w * ad[h * DH + d];
        }
        wsrc[wo + k * H + h] = ss;
        wdst[wo + k * H + h] = sd;
    }
    for (int c = 0; c < C; c++)
        wt[wto + k * C + c] = (half_t)lw[(size_t)(c & 63) * C + (c >> 6) * 64 + k];
    if (k == 0) {
        int co = (L == 0) ? 0 : (L == 1) ? 8 : 16;
        for (int w = 0; w < 2; w++)
            for (int h = 0; h < H; h++) {
                float s = 0.f;
                for (int d = 0; d < DH; d++)
                    s += ew[w * H * DH + h * DH + d] * ae[h * DH + d];
                coef[co + w * H + h] = s;
            }
    }
}

// ---------------- a_src/a_dst from h16: one thread per node ----------------

template <int H>
__global__ void k_att_h(const half_t* __restrict__ h, const float* __restrict__ wsrc,
                        const float* __restrict__ wdst,
                        float* __restrict__ a_src, float* __restrict__ a_dst) {
    int n = blockIdx.x * blockDim.x + threadIdx.x;
    if (n >= NN) return;
    float as[H], ad[H];
#pragma unroll
    for (int hh = 0; hh < H; hh++) { as[hh] = 0.f; ad[hh] = 0.f; }
    const half_t* hr = h + (size_t)n * DH;
    for (int q = 0; q < DH / 8; q++) {
        float4 raw = *(const float4*)(hr + q * 8);
        const half_t* hp = (const half_t*)&raw;
#pragma unroll
        for (int t = 0; t < 8; t++) {
            float hv = (float)hp[t];
            int k = q * 8 + t;
#pragma unroll
            for (int hh = 0; hh < H; hh++) {
                as[hh] += hv * wsrc[k * H + hh];
                ad[hh] += hv * wdst[k * H + hh];
            }
        }
    }
#pragma unroll
    for (int hh = 0; hh < H; hh++) {
        a_src[n * H + hh] = as[hh];
        a_dst[n * H + hh] = ad[hh];
    }
}

// ---------------- per-node den + alpha (fp16): SINGLE CSR pass + linear rescale ----------------

template <int H>
__global__ void k_mden(const int* __restrict__ row, const int2* __restrict__ csr,
                       const float* __restrict__ a_src, const float* __restrict__ a_dst,
                       const float* __restrict__ coef, half_t* __restrict__ abuf) {
    int n = blockIdx.x * blockDim.x + threadIdx.x;
    if (n >= NN) return;
    int r0 = row[n], r1 = row[n + 1];
    float ad[H], cf[2 * H], den[H];
#pragma unroll
    for (int h = 0; h < H; h++) { ad[h] = a_dst[n * H + h]; den[h] = 0.f; }
#pragma unroll
    for (int i = 0; i < 2 * H; i++) cf[i] = coef[i];
    for (int j = r0; j < r1; j++) {
        int2 rec = csr[j];
        int s = rec.x;
        float e0, e1;
        unpack_ea(rec.y, e0, e1);
        half_t a4[H];
#pragma unroll
        for (int h = 0; h < H; h++) {
            float lg = a_src[s * H + h] + ad[h] + e0 * cf[h] + e1 * cf[H + h];
            lg = (lg > 0.f) ? lg : 0.2f * lg;
            half_t ex = (half_t)(__expf(lg) * 0.03125f);
            den[h] += (float)ex;
            a4[h] = ex;
        }
        if constexpr (H == 4) {
            *(float2*)(abuf + (size_t)j * 4) = *(float2*)a4;
        } else {
            abuf[j] = a4[0];
        }
    }
    float inv[H];
#pragma unroll
    for (int h = 0; h < H; h++) inv[h] = 1.f / (den[h] + 1e-16f);
    for (int j = r0; j < r1; j++) {
        if constexpr (H == 4) {
            float2 raw = *(float2*)(abuf + (size_t)j * 4);
            half_t* ap = (half_t*)&raw;
            half_t a4[4];
#pragma unroll
            for (int h = 0; h < 4; h++) a4[h] = (half_t)((float)ap[h] * inv[h]);
            *(float2*)(abuf + (size_t)j * 4) = *(float2*)a4;
        } else {
            abuf[j] = (half_t)((float)abuf[j] * inv[0]);
        }
    }
}

// ---------------- aggregate on h: one WAVE per node, lane = k, 4-edge pipelined ----------------

template <int H>
__global__ void k_agg_h(const int* __restrict__ row, const int2* __restrict__ csr,
                        const half_t* __restrict__ abuf, const half_t* __restrict__ h16,
                        half_t* __restrict__ agg) {
    int gid = blockIdx.x * blockDim.x + threadIdx.x;
    int n = gid >> 6;
    int lane = gid & 63;
    if (n >= NN) return;
    int r0 = row[n], r1 = row[n + 1];
    float acc[H];
#pragma unroll
    for (int h = 0; h < H; h++) acc[h] = 0.f;
    int j = r0;
    for (; j + 4 <= r1; j += 4) {
        int s0 = csr[j].x, s1 = csr[j + 1].x, s2 = csr[j + 2].x, s3 = csr[j + 3].x;
        float av[4][H];
        if constexpr (H == 4) {
            float2 r0v = *(const float2*)(abuf + (size_t)(j + 0) * 4);
            float2 r1v = *(const float2*)(abuf + (size_t)(j + 1) * 4);
            float2 r2v = *(const float2*)(abuf + (size_t)(j + 2) * 4);
            float2 r3v = *(const float2*)(abuf + (size_t)(j + 3) * 4);
            const half_t* p0 = (const half_t*)&r0v;
            const half_t* p1 = (const half_t*)&r1v;
            const half_t* p2 = (const half_t*)&r2v;
            const half_t* p3 = (const half_t*)&r3v;
#pragma unroll
            for (int h = 0; h < 4; h++) {
                av[0][h] = (float)p0[h]; av[1][h] = (float)p1[h];
                av[2][h] = (float)p2[h]; av[3][h] = (float)p3[h];
            }
        } else {
            av[0][0] = (float)abuf[j];     av[1][0] = (float)abuf[j + 1];
            av[2][0] = (float)abuf[j + 2]; av[3][0] = (float)abuf[j + 3];
        }
        float hv0 = (float)h16[(size_t)s0 * DH + lane];
        float hv1 = (float)h16[(size_t)s1 * DH + lane];
        float hv2 = (float)h16[(size_t)s2 * DH + lane];
        float hv3 = (float)h16[(size_t)s3 * DH + lane];
#pragma unroll
        for (int h = 0; h < H; h++) acc[h] += av[0][h] * hv0;
#pragma unroll
        for (int h = 0; h < H; h++) acc[h] += av[1][h] * hv1;
#pragma unroll
        for (int h = 0; h < H; h++) acc[h] += av[2][h] * hv2;
#pragma unroll
        for (int h = 0; h < H; h++) acc[h] += av[3][h] * hv3;
    }
    for (; j < r1; j++) {
        int s = csr[j].x;
        float av[H];
        if constexpr (H == 4) {
            float2 raw = *(const float2*)(abuf + (size_t)j * 4);
            const half_t* ap = (const half_t*)&raw;
#pragma unroll
            for (int h = 0; h < H; h++) av[h] = (float)ap[h];
        } else {
            av[0] = (float)abuf[j];
        }
        float hv = (float)h16[(size_t)s * DH + lane];
#pragma unroll
        for (int h = 0; h < H; h++) acc[h] += av[h] * hv;
    }
#pragma unroll
    for (int h = 0; h < H; h++)
        agg[(size_t)n * (H * DH) + h * DH + lane] = (half_t)acc[h];
}

// ---------------- out via MFMA: fp16-only residual chain ----------------

template <int H>
__global__ void k_out_mfma(const half_t* __restrict__ agg, const half_t* __restrict__ wt,
                           const float* __restrict__ bias, const half_t* __restrict__ h16in,
                           half_t* __restrict__ h16out) {
    constexpr int C = H * DH;
    constexpr int KS = C / 32;
    int gid = blockIdx.x * blockDim.x + threadIdx.x;
    int wave = gid >> 6;
    int lane = gid & 63;
    if (wave >= NN / 16) return;
    int n0 = wave * 16;
    int r  = lane & 15;
    int kb = lane >> 4;

    f16x8 afrag[KS];
#pragma unroll
    for (int s = 0; s < KS; s++)
        afrag[s] = *(const f16x8*)(agg + (size_t)(n0 + r) * C + s * 32 + kb * 8);

#pragma unroll
    for (int ct = 0; ct < 4; ct++) {
        f32x4 acc = {0.f, 0.f, 0.f, 0.f};
#pragma unroll
        for (int s = 0; s < KS; s++) {
            f16x8 bfrag = *(const f16x8*)(wt + (size_t)(ct * 16 + r) * C + s * 32 + kb * 8);
            acc = __builtin_amdgcn_mfma_f32_16x16x32_f16(afrag[s], bfrag, acc, 0, 0, 0);
        }
        int j = ct * 16 + r;
        float bj = bias[j];
#pragma unroll
        for (int i = 0; i < 4; i++) {
            int n = n0 + kb * 4 + i;
            float v = acc[i] * (1.0f / H) + bj;
            v = fmaxf(v, 0.f) + (float)h16in[(size_t)n * DH + j];
            h16out[(size_t)n * DH + j] = (half_t)v;
        }
    }
}

// ---------------- final MLP head (reads fp16 h) ----------------

__global__ void k_head_s(const half_t* __restrict__ h, const float* __restrict__ fc1_W,
                         const float* __restrict__ fc1_b, const float* __restrict__ fc2_W,
                         const float* __restrict__ fc2_b, float* __restrict__ out) {
    int n = blockIdx.x * blockDim.x + threadIdx.x;
    if (n >= NN) return;
    float y[32];
#pragma unroll
    for (int c = 0; c < 32; c++) y[c] = fc1_b[c];
    const half_t* hr = h + (size_t)n * DH;
    for (int q = 0; q < DH / 8; q++) {
        float4 raw = *(const float4*)(hr + q * 8);
        const half_t* hp = (const half_t*)&raw;
#pragma unroll
        for (int t = 0; t < 8; t++) {
            float hk = (float)hp[t];
            int k = q * 8 + t;
#pragma unroll
            for (int c = 0; c < 32; c++) y[c] += hk * fc1_W[k * 32 + c];
        }
    }
    float o0 = fc2_b[0], o1 = fc2_b[1];
#pragma unroll
    for (int c = 0; c < 32; c++) {
        float yr = fmaxf(y[c], 0.f);
        o0 += yr * fc2_W[c * 2];
        o1 += yr * fc2_W[c * 2 + 1];
    }
    out[2 * n] = tanhf(o0);
    out[2 * n + 1] = tanhf(o1);
}

// ---------------- launch ----------------

extern "C" void kernel_launch(void* const* d_in, const int* in_sizes, int n_in,
                              void* d_out, int out_size, void* d_ws, size_t ws_size,
                              hipStream_t stream) {
    const float* x     = (const float*)d_in[0];
    const int*   ei    = (const int*)d_in[1];
    const float* ea    = (const float*)d_in[2];
    const float* enc_W = (const float*)d_in[3];
    const float* enc_b = (const float*)d_in[4];
    const float* lin_W[3]    = {(const float*)d_in[5],  (const float*)d_in[11], (const float*)d_in[17]};
    const float* att_src[3]  = {(const float*)d_in[6],  (const float*)d_in[12], (const float*)d_in[18]};
    const float* att_dst[3]  = {(const float*)d_in[7],  (const float*)d_in[13], (const float*)d_in[19]};
    const float* edge_W[3]   = {(const float*)d_in[8],  (const float*)d_in[14], (const float*)d_in[20]};
    const float* att_edge[3] = {(const float*)d_in[9],  (const float*)d_in[15], (const float*)d_in[21]};
    const float* bias[3]     = {(const float*)d_in[10], (const float*)d_in[16], (const float*)d_in[22]};
    const float* fc1_W = (const float*)d_in[23];
    const float* fc1_b = (const float*)d_in[24];
    const float* fc2_W = (const float*)d_in[25];
    const float* fc2_b = (const float*)d_in[26];
    float* out = (float*)d_out;

    char* p = (char*)d_ws;
    auto alloc = [&](size_t bytes) -> void* {
        void* r = (void*)p;
        p += (bytes + 255) & ~(size_t)255;
        return r;
    };
    int*    deg    = (int*)alloc((size_t)NN * 4);
    int*    rank   = (int*)alloc((size_t)NE * 4);
    int*    part   = (int*)alloc((size_t)NCHUNK * 4);
    int*    row    = (int*)alloc((size_t)(NN + 1) * 4);
    int2*   csr    = (int2*)alloc((size_t)ETOT * 8);
    float*  a_srcB = (float*)alloc((size_t)NN * 4 * 4);
    float*  a_dstB = (float*)alloc((size_t)NN * 4 * 4);
    float*  wsrcA  = (float*)alloc(576 * 4);
    float*  wdstA  = (float*)alloc(576 * 4);
    float*  coefA  = (float*)alloc(18 * 4);
    half_t* wtA    = (half_t*)alloc((size_t)(16384 * 2 + 4096) * 2);
    half_t* abuf   = (half_t*)alloc((size_t)ETOT * 4 * 2);
    half_t* aggB   = (half_t*)alloc((size_t)NN * 256 * 2);
    half_t* h16A   = (half_t*)alloc((size_t)NN * DH * 2);
    half_t* h16B   = (half_t*)alloc((size_t)NN * DH * 2);

    const int BT = 256;
    const int nodeBlocks  = (NN + BT - 1) / BT;
    const int edgeBlocks  = (NE + BT - 1) / BT;
    const int chunkBlocks = (NCHUNK + BT - 1) / BT;
    const int ndBlocks    = (NN * DH + BT - 1) / BT;
    const int nodeWaveBlocks = (NN * 64 + BT - 1) / BT;
    const int mfmaBlocks  = ((NN / 16) * 64 + BT - 1) / BT;

    k_zero_init<<<nodeBlocks, BT, 0, stream>>>(deg);
    k_deg<<<edgeBlocks, BT, 0, stream>>>(ei, deg, rank);
    k_scan_a<<<chunkBlocks, BT, 0, stream>>>(deg, part);
    k_scan_b<<<1, 64, 0, stream>>>(part);
    k_scan_c<<<chunkBlocks, BT, 0, stream>>>(deg, part, row);
    k_fill_csr<<<edgeBlocks, BT, 0, stream>>>(ei, ea, row, rank, csr);
    k_fill_self<<<nodeBlocks, BT, 0, stream>>>(deg, row, csr);
    k_encoder<<<ndBlocks, BT, 0, stream>>>(x, enc_W, enc_b, h16A);
    k_prep<<<3, 64, 0, stream>>>(lin_W[0], att_src[0], att_dst[0], edge_W[0], att_edge[0],
                                 lin_W[1], att_src[1], att_dst[1], edge_W[1], att_edge[1],
                                 lin_W[2], att_src[2], att_dst[2], edge_W[2], att_edge[2],
                                 wsrcA, wdstA, coefA, wtA);

    half_t* hin = h16A;
    half_t* hout = h16B;

    for (int L = 0; L < 3; L++) {
        const float* ws = wsrcA + ((L == 0) ? 0 : (L == 1) ? 256 : 512);
        const float* wd = wdstA + ((L == 0) ? 0 : (L == 1) ? 256 : 512);
        const float* cf = coefA + ((L == 0) ? 0 : (L == 1) ? 8 : 16);
        const half_t* wt = wtA + ((L == 0) ? 0 : (L == 1) ? 16384 : 32768);
        if (L < 2) {
            constexpr int H = 4;
            k_att_h<H><<<nodeBlocks, BT, 0, stream>>>(hin, ws, wd, a_srcB, a_dstB);
            k_mden<H><<<nodeBlocks, BT, 0, stream>>>(row, csr, a_srcB, a_dstB, cf, abuf);
            k_agg_h<H><<<nodeWaveBlocks, BT, 0, stream>>>(row, csr, abuf, hin, aggB);
            k_out_mfma<H><<<mfmaBlocks, BT, 0, stream>>>(aggB, wt, bias[L], hin, hout);
        } else {
            constexpr int H = 1;
            k_att_h<H><<<nodeBlocks, BT, 0, stream>>>(hin, ws, wd, a_srcB, a_dstB);
            k_mden<H><<<nodeBlocks, BT, 0, stream>>>(row, csr, a_srcB, a_dstB, cf, abuf);
            k_agg_h<H><<<nodeWaveBlocks, BT, 0, stream>>>(row, csr, abuf, hin, aggB);
            k_out_mfma<H><<<mfmaBlocks, BT, 0, stream>>>(aggB, wt, bias[L], hin, hout);
        }
        half_t* t = hin; hin = hout; hout = t;
    }
    k_head_s<<<nodeBlocks, BT, 0, stream>>>(hin, fc1_W, fc1_b, fc2_W, fc2_b, out);
}

// Round 18
// 530.369 us; speedup vs baseline: 1.5441x; 1.0299x over previous
//
#include <hip/hip_runtime.h>
#include <math.h>

#define NN 100000
#define NE 1000000
#define DH 64
constexpr int ETOT = NE + NN;
constexpr int CHUNK = 100;
constexpr int NCHUNK = (NN + CHUNK - 1) / CHUNK;   // 1000

typedef _Float16 half_t;
typedef _Float16 f16x8 __attribute__((ext_vector_type(8)));
typedef float f32x4 __attribute__((ext_vector_type(4)));

// AoS edge record (8B): {int src; half2 ea} stored as int2

union h2u {
    int i;
    struct { unsigned short lo, hi; } u;
};
__device__ inline int pack_ea(float a, float b) {
    half_t ha = (half_t)a, hb = (half_t)b;
    h2u v;
    v.u.lo = *(unsigned short*)&ha;
    v.u.hi = *(unsigned short*)&hb;
    return v.i;
}
__device__ inline void unpack_ea(int p, float& a, float& b) {
    h2u v; v.i = p;
    half_t ha = *(half_t*)&v.u.lo;
    half_t hb = *(half_t*)&v.u.hi;
    a = (float)ha; b = (float)hb;
}

// ---------------- degree + per-edge rank ----------------

__global__ void k_zero_init(int* __restrict__ deg) {
    int i = blockIdx.x * blockDim.x + threadIdx.x;
    if (i < NN) deg[i] = 0;
}

__global__ void k_deg(const int* __restrict__ ei, int* __restrict__ deg, int* __restrict__ rank) {
    int e = blockIdx.x * blockDim.x + threadIdx.x;
    if (e < NE) rank[e] = atomicAdd(&deg[ei[NE + e]], 1);
}

// ---------------- chunked prefix scan (scalar) ----------------

__global__ void k_scan_a(const int* __restrict__ deg, int* __restrict__ part) {
    int c = blockIdx.x * blockDim.x + threadIdx.x;
    if (c >= NCHUNK) return;
    int lo = c * CHUNK;
    int hi = lo + CHUNK; if (hi > NN) hi = NN;
    int s = 0;
    for (int i = lo; i < hi; i++) s += deg[i];
    part[c] = s;
}

__global__ void k_scan_b(int* __restrict__ part) {
    if (threadIdx.x || blockIdx.x) return;
    int run = 0;
    for (int i = 0; i < NCHUNK; i++) { int t = part[i]; part[i] = run; run += t; }
}

__global__ void k_scan_c(const int* __restrict__ deg, const int* __restrict__ part,
                         int* __restrict__ row) {
    int c = blockIdx.x * blockDim.x + threadIdx.x;
    if (c >= NCHUNK) return;
    int lo = c * CHUNK;
    int hi = lo + CHUNK; if (hi > NN) hi = NN;
    int run = part[c];
    for (int i = lo; i < hi; i++) {
        row[i] = run + i;
        run += deg[i];
    }
    if (c == NCHUNK - 1) row[NN] = run + NN;
}

__global__ void k_fill_csr(const int* __restrict__ ei, const float* __restrict__ ea,
                           const int* __restrict__ row, const int* __restrict__ rank,
                           int2* __restrict__ csr) {
    int e = blockIdx.x * blockDim.x + threadIdx.x;
    if (e < NE) {
        int s = ei[e];
        int d = ei[NE + e];
        int pos = row[d] + rank[e];
        int2 rec;
        rec.x = s;
        rec.y = pack_ea(ea[2 * e], ea[2 * e + 1]);
        csr[pos] = rec;
    }
}

__global__ void k_fill_self(const int* __restrict__ deg, const int* __restrict__ row,
                            int2* __restrict__ csr) {
    int n = blockIdx.x * blockDim.x + threadIdx.x;
    if (n >= NN) return;
    int r0 = row[n];
    int dg = deg[n];
    float s0 = 0.f, s1 = 0.f;
    for (int j = r0; j < r0 + dg; j++) {
        float e0, e1;
        unpack_ea(csr[j].y, e0, e1);
        s0 += e0; s1 += e1;
    }
    float dv = fmaxf((float)dg, 1.0f);
    int2 self;
    self.x = n;
    self.y = pack_ea(s0 / dv, s1 / dv);
    csr[r0 + dg] = self;
}

// ---------------- encoder ----------------

__global__ void k_encoder(const float* __restrict__ x, const float* __restrict__ W,
                          const float* __restrict__ b, half_t* __restrict__ h16) {
    int idx = blockIdx.x * blockDim.x + threadIdx.x;
    int n = idx >> 6, d = idx & 63;
    if (n < NN) {
        float v = x[2 * n] * W[d] + x[2 * n + 1] * W[DH + d] + b[d];
        h16[idx] = (half_t)fmaxf(v, 0.f);
    }
}

// ---------------- fused prep ----------------

__global__ void k_prep(const float* __restrict__ lw0, const float* __restrict__ as0,
                       const float* __restrict__ ad0, const float* __restrict__ ew0,
                       const float* __restrict__ ae0,
                       const float* __restrict__ lw1, const float* __restrict__ as1,
                       const float* __restrict__ ad1, const float* __restrict__ ew1,
                       const float* __restrict__ ae1,
                       const float* __restrict__ lw2, const float* __restrict__ as2,
                       const float* __restrict__ ad2, const float* __restrict__ ew2,
                       const float* __restrict__ ae2,
                       float* __restrict__ wsrc, float* __restrict__ wdst,
                       float* __restrict__ coef, half_t* __restrict__ wt) {
    int L = blockIdx.x;
    int k = threadIdx.x;
    if (k >= DH) return;
    const float* lw = (L == 0) ? lw0 : (L == 1) ? lw1 : lw2;
    const float* as = (L == 0) ? as0 : (L == 1) ? as1 : as2;
    const float* ad = (L == 0) ? ad0 : (L == 1) ? ad1 : ad2;
    const float* ew = (L == 0) ? ew0 : (L == 1) ? ew1 : ew2;
    const float* ae = (L == 0) ? ae0 : (L == 1) ? ae1 : ae2;
    int H = (L < 2) ? 4 : 1;
    int C = H * DH;
    int wo = (L == 0) ? 0 : (L == 1) ? 256 : 512;
    int wto = (L == 0) ? 0 : (L == 1) ? 16384 : 32768;
    for (int h = 0; h < H; h++) {
        float ss = 0.f, sd = 0.f;
        for (int d = 0; d < DH; d++) {
            float w = lw[(size_t)k * C + h * DH + d];
            ss += w * as[h * DH + d];
            sd += w * ad[h * DH + d];
        }
        wsrc[wo + k * H + h] = ss;
        wdst[wo + k * H + h] = sd;
    }
    for (int c = 0; c < C; c++)
        wt[wto + k * C + c] = (half_t)lw[(size_t)(c & 63) * C + (c >> 6) * 64 + k];
    if (k == 0) {
        int co = (L == 0) ? 0 : (L == 1) ? 8 : 16;
        for (int w = 0; w < 2; w++)
            for (int h = 0; h < H; h++) {
                float s = 0.f;
                for (int d = 0; d < DH; d++)
                    s += ew[w * H * DH + h * DH + d] * ae[h * DH + d];
                coef[co + w * H + h] = s;
            }
    }
}

// ---------------- a_src/a_dst from h16 ----------------

template <int H>
__global__ void k_att_h(const half_t* __restrict__ h, const float* __restrict__ wsrc,
                        const float* __restrict__ wdst,
                        float* __restrict__ a_src, float* __restrict__ a_dst) {
    int n = blockIdx.x * blockDim.x + threadIdx.x;
    if (n >= NN) return;
    float as[H], ad[H];
#pragma unroll
    for (int hh = 0; hh < H; hh++) { as[hh] = 0.f; ad[hh] = 0.f; }
    const half_t* hr = h + (size_t)n * DH;
    for (int q = 0; q < DH / 8; q++) {
        float4 raw = *(const float4*)(hr + q * 8);
        const half_t* hp = (const half_t*)&raw;
#pragma unroll
        for (int t = 0; t < 8; t++) {
            float hv = (float)hp[t];
            int k = q * 8 + t;
#pragma unroll
            for (int hh = 0; hh < H; hh++) {
                as[hh] += hv * wsrc[k * H + hh];
                ad[hh] += hv * wdst[k * H + hh];
            }
        }
    }
#pragma unroll
    for (int hh = 0; hh < H; hh++) {
        a_src[n * H + hh] = as[hh];
        a_dst[n * H + hh] = ad[hh];
    }
}

// ---------------- mden: SINGLE csr pass, raw scaled ex (fp16) + den; no rescale pass ----------

template <int H>
__global__ void k_mden(const int* __restrict__ row, const int2* __restrict__ csr,
                       const float* __restrict__ a_src, const float* __restrict__ a_dst,
                       const float* __restrict__ coef, half_t* __restrict__ abuf,
                       float* __restrict__ denout) {
    int n = blockIdx.x * blockDim.x + threadIdx.x;
    if (n >= NN) return;
    int r0 = row[n], r1 = row[n + 1];
    float ad[H], cf[2 * H], den[H];
#pragma unroll
    for (int h = 0; h < H; h++) { ad[h] = a_dst[n * H + h]; den[h] = 0.f; }
#pragma unroll
    for (int i = 0; i < 2 * H; i++) cf[i] = coef[i];
    for (int j = r0; j < r1; j++) {
        int2 rec = csr[j];
        int s = rec.x;
        float e0, e1;
        unpack_ea(rec.y, e0, e1);
        half_t a4[H];
#pragma unroll
        for (int h = 0; h < H; h++) {
            float lg = a_src[s * H + h] + ad[h] + e0 * cf[h] + e1 * cf[H + h];
            lg = (lg > 0.f) ? lg : 0.2f * lg;
            half_t ex = (half_t)(__expf(lg) * 0.03125f);   // scale cancels in alpha
            den[h] += (float)ex;                            // sum the ROUNDED values
            a4[h] = ex;
        }
        if constexpr (H == 4) {
            *(float2*)(abuf + (size_t)j * 4) = *(float2*)a4;
        } else {
            abuf[j] = a4[0];
        }
    }
#pragma unroll
    for (int h = 0; h < H; h++) denout[n * H + h] = den[h];
}

// ---------------- aggregate: one WAVE per node, 8-edge pipelined, final inv multiply ----------

template <int H>
__global__ void k_agg_h(const int* __restrict__ row, const int2* __restrict__ csr,
                        const half_t* __restrict__ abuf, const float* __restrict__ denv,
                        const half_t* __restrict__ h16, half_t* __restrict__ agg) {
    int gid = blockIdx.x * blockDim.x + threadIdx.x;
    int n = gid >> 6;
    int lane = gid & 63;
    if (n >= NN) return;
    int r0 = row[n], r1 = row[n + 1];
    float acc[H];
#pragma unroll
    for (int h = 0; h < H; h++) acc[h] = 0.f;
    int j = r0;
    for (; j + 8 <= r1; j += 8) {
        int s[8];
#pragma unroll
        for (int u = 0; u < 8; u++) s[u] = csr[j + u].x;
        float av[8][H];
#pragma unroll
        for (int u = 0; u < 8; u++) {
            if constexpr (H == 4) {
                float2 raw = *(const float2*)(abuf + (size_t)(j + u) * 4);
                const half_t* ap = (const half_t*)&raw;
#pragma unroll
                for (int h = 0; h < 4; h++) av[u][h] = (float)ap[h];
            } else {
                av[u][0] = (float)abuf[j + u];
            }
        }
        float hv[8];
#pragma unroll
        for (int u = 0; u < 8; u++) hv[u] = (float)h16[(size_t)s[u] * DH + lane];
#pragma unroll
        for (int u = 0; u < 8; u++)
#pragma unroll
            for (int h = 0; h < H; h++) acc[h] += av[u][h] * hv[u];
    }
    for (; j + 4 <= r1; j += 4) {
        int s[4];
#pragma unroll
        for (int u = 0; u < 4; u++) s[u] = csr[j + u].x;
        float av[4][H];
#pragma unroll
        for (int u = 0; u < 4; u++) {
            if constexpr (H == 4) {
                float2 raw = *(const float2*)(abuf + (size_t)(j + u) * 4);
                const half_t* ap = (const half_t*)&raw;
#pragma unroll
                for (int h = 0; h < 4; h++) av[u][h] = (float)ap[h];
            } else {
                av[u][0] = (float)abuf[j + u];
            }
        }
        float hv[4];
#pragma unroll
        for (int u = 0; u < 4; u++) hv[u] = (float)h16[(size_t)s[u] * DH + lane];
#pragma unroll
        for (int u = 0; u < 4; u++)
#pragma unroll
            for (int h = 0; h < H; h++) acc[h] += av[u][h] * hv[u];
    }
    for (; j < r1; j++) {
        int s = csr[j].x;
        float av[H];
        if constexpr (H == 4) {
            float2 raw = *(const float2*)(abuf + (size_t)j * 4);
            const half_t* ap = (const half_t*)&raw;
#pragma unroll
            for (int h = 0; h < H; h++) av[h] = (float)ap[h];
        } else {
            av[0] = (float)abuf[j];
        }
        float hv = (float)h16[(size_t)s * DH + lane];
#pragma unroll
        for (int h = 0; h < H; h++) acc[h] += av[h] * hv;
    }
#pragma unroll
    for (int h = 0; h < H; h++) {
        float inv = 1.f / (denv[n * H + h] + 1e-16f);
        agg[(size_t)n * (H * DH) + h * DH + lane] = (half_t)(acc[h] * inv);
    }
}

// ---------------- out via MFMA ----------------

template <int H>
__global__ void k_out_mfma(const half_t* __restrict__ agg, const half_t* __restrict__ wt,
                           const float* __restrict__ bias, const half_t* __restrict__ h16in,
                           half_t* __restrict__ h16out) {
    constexpr int C = H * DH;
    constexpr int KS = C / 32;
    int gid = blockIdx.x * blockDim.x + threadIdx.x;
    int wave = gid >> 6;
    int lane = gid & 63;
    if (wave >= NN / 16) return;
    int n0 = wave * 16;
    int r  = lane & 15;
    int kb = lane >> 4;

    f16x8 afrag[KS];
#pragma unroll
    for (int s = 0; s < KS; s++)
        afrag[s] = *(const f16x8*)(agg + (size_t)(n0 + r) * C + s * 32 + kb * 8);

#pragma unroll
    for (int ct = 0; ct < 4; ct++) {
        f32x4 acc = {0.f, 0.f, 0.f, 0.f};
#pragma unroll
        for (int s = 0; s < KS; s++) {
            f16x8 bfrag = *(const f16x8*)(wt + (size_t)(ct * 16 + r) * C + s * 32 + kb * 8);
            acc = __builtin_amdgcn_mfma_f32_16x16x32_f16(afrag[s], bfrag, acc, 0, 0, 0);
        }
        int j = ct * 16 + r;
        float bj = bias[j];
#pragma unroll
        for (int i = 0; i < 4; i++) {
            int n = n0 + kb * 4 + i;
            float v = acc[i] * (1.0f / H) + bj;
            v = fmaxf(v, 0.f) + (float)h16in[(size_t)n * DH + j];
            h16out[(size_t)n * DH + j] = (half_t)v;
        }
    }
}

// ---------------- final MLP head ----------------

__global__ void k_head_s(const half_t* __restrict__ h, const float* __restrict__ fc1_W,
                         const float* __restrict__ fc1_b, const float* __restrict__ fc2_W,
                         const float* __restrict__ fc2_b, float* __restrict__ out) {
    int n = blockIdx.x * blockDim.x + threadIdx.x;
    if (n >= NN) return;
    float y[32];
#pragma unroll
    for (int c = 0; c < 32; c++) y[c] = fc1_b[c];
    const half_t* hr = h + (size_t)n * DH;
    for (int q = 0; q < DH / 8; q++) {
        float4 raw = *(const float4*)(hr + q * 8);
        const half_t* hp = (const half_t*)&raw;
#pragma unroll
        for (int t = 0; t < 8; t++) {
            float hk = (float)hp[t];
            int k = q * 8 + t;
#pragma unroll
            for (int c = 0; c < 32; c++) y[c] += hk * fc1_W[k * 32 + c];
        }
    }
    float o0 = fc2_b[0], o1 = fc2_b[1];
#pragma unroll
    for (int c = 0; c < 32; c++) {
        float yr = fmaxf(y[c], 0.f);
        o0 += yr * fc2_W[c * 2];
        o1 += yr * fc2_W[c * 2 + 1];
    }
    out[2 * n] = tanhf(o0);
    out[2 * n + 1] = tanhf(o1);
}

// ---------------- launch ----------------

extern "C" void kernel_launch(void* const* d_in, const int* in_sizes, int n_in,
                              void* d_out, int out_size, void* d_ws, size_t ws_size,
                              hipStream_t stream) {
    const float* x     = (const float*)d_in[0];
    const int*   ei    = (const int*)d_in[1];
    const float* ea    = (const float*)d_in[2];
    const float* enc_W = (const float*)d_in[3];
    const float* enc_b = (const float*)d_in[4];
    const float* lin_W[3]    = {(const float*)d_in[5],  (const float*)d_in[11], (const float*)d_in[17]};
    const float* att_src[3]  = {(const float*)d_in[6],  (const float*)d_in[12], (const float*)d_in[18]};
    const float* att_dst[3]  = {(const float*)d_in[7],  (const float*)d_in[13], (const float*)d_in[19]};
    const float* edge_W[3]   = {(const float*)d_in[8],  (const float*)d_in[14], (const float*)d_in[20]};
    const float* att_edge[3] = {(const float*)d_in[9],  (const float*)d_in[15], (const float*)d_in[21]};
    const float* bias[3]     = {(const float*)d_in[10], (const float*)d_in[16], (const float*)d_in[22]};
    const float* fc1_W = (const float*)d_in[23];
    const float* fc1_b = (const float*)d_in[24];
    const float* fc2_W = (const float*)d_in[25];
    const float* fc2_b = (const float*)d_in[26];
    float* out = (float*)d_out;

    char* p = (char*)d_ws;
    auto alloc = [&](size_t bytes) -> void* {
        void* r = (void*)p;
        p += (bytes + 255) & ~(size_t)255;
        return r;
    };
    int*    deg    = (int*)alloc((size_t)NN * 4);
    int*    rank   = (int*)alloc((size_t)NE * 4);
    int*    part   = (int*)alloc((size_t)NCHUNK * 4);
    int*    row    = (int*)alloc((size_t)(NN + 1) * 4);
    int2*   csr    = (int2*)alloc((size_t)ETOT * 8);
    float*  a_srcB = (float*)alloc((size_t)NN * 4 * 4);
    float*  a_dstB = (float*)alloc((size_t)NN * 4 * 4);
    float*  denB   = (float*)alloc((size_t)NN * 4 * 4);
    float*  wsrcA  = (float*)alloc(576 * 4);
    float*  wdstA  = (float*)alloc(576 * 4);
    float*  coefA  = (float*)alloc(18 * 4);
    half_t* wtA    = (half_t*)alloc((size_t)(16384 * 2 + 4096) * 2);
    half_t* abuf   = (half_t*)alloc((size_t)ETOT * 4 * 2);
    half_t* aggB   = (half_t*)alloc((size_t)NN * 256 * 2);
    half_t* h16A   = (half_t*)alloc((size_t)NN * DH * 2);
    half_t* h16B   = (half_t*)alloc((size_t)NN * DH * 2);

    const int BT = 256;
    const int nodeBlocks  = (NN + BT - 1) / BT;
    const int edgeBlocks  = (NE + BT - 1) / BT;
    const int chunkBlocks = (NCHUNK + BT - 1) / BT;
    const int ndBlocks    = (NN * DH + BT - 1) / BT;
    const int nodeWaveBlocks = (NN * 64 + BT - 1) / BT;
    const int mfmaBlocks  = ((NN / 16) * 64 + BT - 1) / BT;

    k_zero_init<<<nodeBlocks, BT, 0, stream>>>(deg);
    k_deg<<<edgeBlocks, BT, 0, stream>>>(ei, deg, rank);
    k_scan_a<<<chunkBlocks, BT, 0, stream>>>(deg, part);
    k_scan_b<<<1, 64, 0, stream>>>(part);
    k_scan_c<<<chunkBlocks, BT, 0, stream>>>(deg, part, row);
    k_fill_csr<<<edgeBlocks, BT, 0, stream>>>(ei, ea, row, rank, csr);
    k_fill_self<<<nodeBlocks, BT, 0, stream>>>(deg, row, csr);
    k_encoder<<<ndBlocks, BT, 0, stream>>>(x, enc_W, enc_b, h16A);
    k_prep<<<3, 64, 0, stream>>>(lin_W[0], att_src[0], att_dst[0], edge_W[0], att_edge[0],
                                 lin_W[1], att_src[1], att_dst[1], edge_W[1], att_edge[1],
                                 lin_W[2], att_src[2], att_dst[2], edge_W[2], att_edge[2],
                                 wsrcA, wdstA, coefA, wtA);

    half_t* hin = h16A;
    half_t* hout = h16B;

    for (int L = 0; L < 3; L++) {
        const float* ws = wsrcA + ((L == 0) ? 0 : (L == 1) ? 256 : 512);
        const float* wd = wdstA + ((L == 0) ? 0 : (L == 1) ? 256 : 512);
        const float* cf = coefA + ((L == 0) ? 0 : (L == 1) ? 8 : 16);
        const half_t* wt = wtA + ((L == 0) ? 0 : (L == 1) ? 16384 : 32768);
        if (L < 2) {
            constexpr int H = 4;
            k_att_h<H><<<nodeBlocks, BT, 0, stream>>>(hin, ws, wd, a_srcB, a_dstB);
            k_mden<H><<<nodeBlocks, BT, 0, stream>>>(row, csr, a_srcB, a_dstB, cf, abuf, denB);
            k_agg_h<H><<<nodeWaveBlocks, BT, 0, stream>>>(row, csr, abuf, denB, hin, aggB);
            k_out_mfma<H><<<mfmaBlocks, BT, 0, stream>>>(aggB, wt, bias[L], hin, hout);
        } else {
            constexpr int H = 1;
            k_att_h<H><<<nodeBlocks, BT, 0, stream>>>(hin, ws, wd, a_srcB, a_dstB);
            k_mden<H><<<nodeBlocks, BT, 0, stream>>>(row, csr, a_srcB, a_dstB, cf, abuf, denB);
            k_agg_h<H><<<nodeWaveBlocks, BT, 0, stream>>>(row, csr, abuf, denB, hin, aggB);
            k_out_mfma<H><<<mfmaBlocks, BT, 0, stream>>>(aggB, wt, bias[L], hin, hout);
        }
        half_t* t = hin; hin = hout; hout = t;
    }
    k_head_s<<<nodeBlocks, BT, 0, stream>>>(hin, fc1_W, fc1_b, fc2_W, fc2_b, out);
}